// Round 4
// baseline (1627.630 us; speedup 1.0000x reference)
//
#include <hip/hip_runtime.h>

typedef unsigned short u16;
typedef __attribute__((ext_vector_type(8))) short short8;
typedef __attribute__((ext_vector_type(4))) float f32x4;
typedef const __attribute__((address_space(1))) void* gas_p;
typedef __attribute__((address_space(3))) void* las_p;

// ---------- constants ----------
#define LL (6)
#define BB (4)
#define TT (1024)
#define EE (512)
#define HH (8)
#define HD (64)
#define T4 (256)
#define FF (2048)
#define BT (BB*TT)           // 4096
#define LAMBDA (0.001f)

// ---------- helpers ----------
struct Off3 { long long hi, lo; int mod; };  // offset = (z/mod)*hi + (z%mod)*lo
__device__ __forceinline__ long long off3(Off3 o, int z) {
  return (long long)(z / o.mod) * o.hi + (long long)(z % o.mod) * o.lo;
}
__device__ __forceinline__ float b2f(u16 u) { return __uint_as_float((unsigned)u << 16); }
__device__ __forceinline__ u16 f2b(float f) {
  unsigned u = __float_as_uint(f);
  return (u16)((u + 0x7fffu + ((u >> 16) & 1u)) >> 16);   // RNE
}
__device__ __forceinline__ float tof(float v) { return v; }
__device__ __forceinline__ float tof(u16 v) { return b2f(v); }

// ---------- MFMA GEMM: C = act(alpha * A @ Bt^T + bias) ----------
// A: bf16 (M,K) lda; Bt: bf16 (N,K) ldb; C: f32/bf16 ldc. BK=32 fixed.
// Staging: global_load_lds width=16, linear LDS dest, inverse-swizzled source.
// ACT: 0=none 1=relu 3=exp(sigmoid(v))
template<int BM, int BN, bool C_BF16, int ACT>
__global__ __launch_bounds__(256) void gemm_bt(
    const u16* __restrict__ A, const u16* __restrict__ Bt, void* __restrict__ Cv,
    const float* __restrict__ bias, float alpha,
    int K, int lda, int ldb, int ldc,
    Off3 oa, Off3 ob, Off3 oc, Off3 obias)
{
  constexpr int WM = BM / 2, WN = BN / 2;
  constexpr int MR = WM / 16, NR = WN / 16;
  __shared__ alignas(16) u16 lA[BM * 32];
  __shared__ alignas(16) u16 lB[BN * 32];

  const int z = blockIdx.z;
  A  += off3(oa, z);
  Bt += off3(ob, z);
  const int tid = threadIdx.x;
  const int lane = tid & 63, wave = tid >> 6;
  const int wm = wave >> 1, wn = wave & 1;           // 2x2 wave grid
  const long long bm = (long long)blockIdx.x * BM;
  const long long bn = (long long)blockIdx.y * BN;

  f32x4 acc[MR][NR] = {};

  const int rsub = lane >> 2;          // 0..15 row within 16-row chunk
  const int segd = lane & 3;           // dest 16B segment within 64B row

  for (int k0 = 0; k0 < K; k0 += 32) {
    __syncthreads();
    #pragma unroll
    for (int j = 0; j < BM / 64; ++j) {
      const int i = wave * (BM / 64) + j;
      const int row = i * 16 + rsub;
      const int segs = segd ^ ((row >> 1) & 3);
      const u16* g = A + (bm + row) * (long long)lda + k0 + segs * 8;
      __builtin_amdgcn_global_load_lds((gas_p)g, (las_p)(lA + i * 512), 16, 0, 0);
    }
    #pragma unroll
    for (int j = 0; j < BN / 64; ++j) {
      const int i = wave * (BN / 64) + j;
      const int row = i * 16 + rsub;
      const int segs = segd ^ ((row >> 1) & 3);
      const u16* g = Bt + (bn + row) * (long long)ldb + k0 + segs * 8;
      __builtin_amdgcn_global_load_lds((gas_p)g, (las_p)(lB + i * 512), 16, 0, 0);
    }
    __syncthreads();

    const int seg = lane >> 4;
    short8 af[MR], bfr[NR];
    #pragma unroll
    for (int m = 0; m < MR; ++m) {
      const int row = wm * WM + m * 16 + (lane & 15);
      af[m] = *(const short8*)(lA + row * 32 + (seg ^ ((row >> 1) & 3)) * 8);
    }
    #pragma unroll
    for (int n = 0; n < NR; ++n) {
      const int row = wn * WN + n * 16 + (lane & 15);
      bfr[n] = *(const short8*)(lB + row * 32 + (seg ^ ((row >> 1) & 3)) * 8);
    }
    #pragma unroll
    for (int m = 0; m < MR; ++m)
      #pragma unroll
      for (int n = 0; n < NR; ++n)
        acc[m][n] = __builtin_amdgcn_mfma_f32_16x16x32_bf16(af[m], bfr[n], acc[m][n], 0, 0, 0);
  }

  const float* bp = bias ? (bias + off3(obias, z)) : nullptr;
  const long long cb = off3(oc, z);
  #pragma unroll
  for (int m = 0; m < MR; ++m) {
    const long long row0 = bm + wm * WM + m * 16 + (lane >> 4) * 4;
    #pragma unroll
    for (int n = 0; n < NR; ++n) {
      const long long col = bn + wn * WN + n * 16 + (lane & 15);
      const float bv = bp ? bp[col] : 0.0f;
      #pragma unroll
      for (int r = 0; r < 4; ++r) {
        float v = acc[m][n][r] * alpha + bv;
        if (ACT == 1) v = fmaxf(v, 0.0f);
        if (ACT == 3) v = __expf(1.0f / (1.0f + __expf(-v)));
        const long long idx = cb + (row0 + r) * (long long)ldc + col;
        if constexpr (C_BF16) ((u16*)Cv)[idx] = f2b(v);
        else                  ((float*)Cv)[idx] = v;
      }
    }
  }
}

// ---------- fused attention tail ----------
// P[t,s] = exp(sigmoid(lat[t,:]·wd[:,s] + bd[s])); o[t,d] = (P/rowsum)·v[s,d]
// per block: z=bh, 64 t-rows. lat (32,1024,256); wdT (8,1024,256) row=s col=u;
// bd (8,1024); vT (32,64,1024) row=d col=s; o (4096,512) scattered.
__global__ __launch_bounds__(256) void attn_tail_kernel(
    const u16* __restrict__ lat, const u16* __restrict__ wdT,
    const float* __restrict__ bd, const u16* __restrict__ vT,
    u16* __restrict__ o)
{
  __shared__ alignas(16) u16 latL[64 * 256];   // 32 KB
  __shared__ alignas(16) u16 wdL[128 * 128];   // 32 KB
  __shared__ alignas(16) u16 pL[64 * 128];     // 16 KB
  __shared__ float rsL[2][64];

  const int z = blockIdx.y, tb = blockIdx.x;
  const int h = z & 7;
  const int tid = threadIdx.x, lane = tid & 63, wave = tid >> 6;
  const int wm = wave >> 1, wn = wave & 1;
  const u16* latz = lat + (size_t)z * 262144 + (size_t)tb * 64 * 256;
  const u16* wdh = wdT + (size_t)h * 262144;
  const float* bdh = bd + (size_t)h * 1024;
  const u16* vz = vT + (size_t)z * 65536;

  // stage lat block (64 rows x 32 granules of 16B), granule ^= (row&7)
  #pragma unroll
  for (int j = 0; j < 8; ++j) {
    const int i = wave * 8 + j;
    const int row = i * 2 + (lane >> 5);
    const int l = (lane & 31) ^ (row & 7);
    __builtin_amdgcn_global_load_lds((gas_p)(latz + row * 256 + l * 8),
                                     (las_p)(latL + i * 512), 16, 0, 0);
  }

  const f32x4 z4 = {0.f, 0.f, 0.f, 0.f};
  f32x4 oacc[2][2] = {};
  float rsum[2][4] = {};

  for (int sc = 0; sc < 8; ++sc) {
    f32x4 pacc[2][4];
    #pragma unroll
    for (int m = 0; m < 2; ++m)
      #pragma unroll
      for (int n = 0; n < 4; ++n) pacc[m][n] = z4;

    #pragma unroll
    for (int kt = 0; kt < 2; ++kt) {
      __syncthreads();                                   // wdL/pL free
      #pragma unroll
      for (int j = 0; j < 8; ++j) {                      // stage wd 128x128
        const int i = wave * 8 + j;
        const int rloc = i * 4 + (lane >> 4);
        const int l = (lane & 15) ^ (rloc & 7);
        __builtin_amdgcn_global_load_lds(
            (gas_p)(wdh + (size_t)(sc * 128 + rloc) * 256 + kt * 128 + l * 8),
            (las_p)(wdL + i * 512), 16, 0, 0);
      }
      __syncthreads();                                   // tile ready
      #pragma unroll
      for (int kk = 0; kk < 4; ++kk) {
        short8 af[2], bfr[4];
        #pragma unroll
        for (int m = 0; m < 2; ++m) {
          const int row = wm * 32 + m * 16 + (lane & 15);
          const int lg = kt * 16 + kk * 4 + (lane >> 4);
          af[m] = *(const short8*)(latL + row * 256 + (lg ^ (row & 7)) * 8);
        }
        #pragma unroll
        for (int n = 0; n < 4; ++n) {
          const int row = wn * 64 + n * 16 + (lane & 15);
          const int lg = kk * 4 + (lane >> 4);
          bfr[n] = *(const short8*)(wdL + row * 128 + (lg ^ (row & 7)) * 8);
        }
        #pragma unroll
        for (int m = 0; m < 2; ++m)
          #pragma unroll
          for (int n = 0; n < 4; ++n)
            pacc[m][n] = __builtin_amdgcn_mfma_f32_16x16x32_bf16(af[m], bfr[n], pacc[m][n], 0, 0, 0);
      }
    }

    // epilogue: bias + exp(sigmoid) + rowsum partial + pL write (bf16)
    #pragma unroll
    for (int n = 0; n < 4; ++n) {
      const int sloc = wn * 64 + n * 16 + (lane & 15);
      const float bv = bdh[sc * 128 + sloc];
      #pragma unroll
      for (int m = 0; m < 2; ++m) {
        #pragma unroll
        for (int r = 0; r < 4; ++r) {
          const float val = pacc[m][n][r] + bv;
          const float sig = 1.0f / (1.0f + __expf(-val));
          const float pe = __expf(sig);
          rsum[m][r] += pe;
          const int t = wm * 32 + m * 16 + (lane >> 4) * 4 + r;
          pL[t * 128 + (((sloc >> 3) ^ (t & 7)) << 3) + (sloc & 7)] = f2b(pe);
        }
      }
    }
    __syncthreads();                                     // pL ready

    // PV: oacc += P(64x128) @ vT-chunk
    #pragma unroll
    for (int ss = 0; ss < 4; ++ss) {
      short8 pa[2], vb[2];
      #pragma unroll
      for (int m = 0; m < 2; ++m) {
        const int t = wm * 32 + m * 16 + (lane & 15);
        const int lg = ss * 4 + (lane >> 4);
        pa[m] = *(const short8*)(pL + t * 128 + (lg ^ (t & 7)) * 8);
      }
      #pragma unroll
      for (int n = 0; n < 2; ++n) {
        const int d = wn * 32 + n * 16 + (lane & 15);
        vb[n] = *(const short8*)(vz + (size_t)d * 1024 + sc * 128 + ss * 32 + (lane >> 4) * 8);
      }
      #pragma unroll
      for (int m = 0; m < 2; ++m)
        #pragma unroll
        for (int n = 0; n < 2; ++n)
          oacc[m][n] = __builtin_amdgcn_mfma_f32_16x16x32_bf16(pa[m], vb[n], oacc[m][n], 0, 0, 0);
    }
  }

  // cross-wave rowsum combine (wn halves), then scale + store
  #pragma unroll
  for (int m = 0; m < 2; ++m)
    #pragma unroll
    for (int r = 0; r < 4; ++r) {
      float s = rsum[m][r];
      #pragma unroll
      for (int off = 1; off < 16; off <<= 1) s += __shfl_xor(s, off);
      if ((lane & 15) == 0)
        rsL[wn][wm * 32 + m * 16 + (lane >> 4) * 4 + r] = s;
    }
  __syncthreads();

  const long long orow0 = (long long)(z >> 3) * 1024 + tb * 64;
  #pragma unroll
  for (int m = 0; m < 2; ++m) {
    #pragma unroll
    for (int r = 0; r < 4; ++r) {
      const int tl = wm * 32 + m * 16 + (lane >> 4) * 4 + r;
      const float inv = 1.0f / (rsL[0][tl] + rsL[1][tl]);
      #pragma unroll
      for (int n = 0; n < 2; ++n) {
        const int col = (z & 7) * 64 + wn * 32 + n * 16 + (lane & 15);
        o[(orow0 + tl) * 512 + col] = f2b(oacc[m][n][r] * inv);
      }
    }
  }
}

// ---------- embedding: h = tok_emb[x] + pos_emb ----------
__global__ __launch_bounds__(256) void embed_kernel(
    const float* __restrict__ tok, const float* __restrict__ pos,
    const int* __restrict__ x, float* __restrict__ h, u16* __restrict__ hb)
{
  const long long row = blockIdx.x;
  const int t = (int)(row & (TT - 1));
  const long long tokid = x[row];
  const float* te = tok + tokid * EE;
  const float* pe = pos + (long long)t * EE;
  const long long base = row * EE;
  for (int e = threadIdx.x; e < EE; e += 256) {
    float v = te[e] + pe[e];
    h[base + e] = v;
    hb[base + e] = f2b(v);
  }
}

// ---------- residual + layernorm (row = 512) ----------
__global__ __launch_bounds__(256) void addnorm_kernel(
    const float* __restrict__ hin, const float* __restrict__ delta,
    const float* __restrict__ g, const float* __restrict__ bta,
    float* __restrict__ hout, u16* __restrict__ hbout)
{
  __shared__ float sm[8];
  const long long base = (long long)blockIdx.x * EE;
  const int tid = threadIdx.x;
  float x0 = hin[base + tid] + delta[base + tid];
  float x1 = hin[base + tid + 256] + delta[base + tid + 256];
  float s = x0 + x1, ss = x0 * x0 + x1 * x1;
  #pragma unroll
  for (int o = 32; o; o >>= 1) { s += __shfl_down(s, o); ss += __shfl_down(ss, o); }
  if ((tid & 63) == 0) { sm[tid >> 6] = s; sm[4 + (tid >> 6)] = ss; }
  __syncthreads();
  const float S = sm[0] + sm[1] + sm[2] + sm[3];
  const float SS = sm[4] + sm[5] + sm[6] + sm[7];
  const float mu = S * (1.0f / EE);
  const float var = SS * (1.0f / EE) - mu * mu;
  const float inv = rsqrtf(var + 1e-5f);
  const float y0 = (x0 - mu) * inv * g[tid] + bta[tid];
  const float y1 = (x1 - mu) * inv * g[tid + 256] + bta[tid + 256];
  hout[base + tid] = y0;       hout[base + tid + 256] = y1;
  hbout[base + tid] = f2b(y0); hbout[base + tid + 256] = f2b(y1);
}

// ---------- LDS-tiled transpose-convert: dst[z][c*lddst + r] = bf16(src[z][r*ldsrc + c]) ----------
template<typename ST>
__global__ __launch_bounds__(256) void transposeT_kernel(
    u16* __restrict__ dst, const ST* __restrict__ src,
    int ldsrc, int lddst, Off3 dstz, Off3 srcz)
{
  __shared__ float t[32][33];
  const int z = blockIdx.z;
  const ST* s = src + off3(srcz, z);
  u16* d = dst + off3(dstz, z);
  const int r0 = blockIdx.x * 32, c0 = blockIdx.y * 32;
  const int tx = threadIdx.x & 31, ty = threadIdx.x >> 5;
  #pragma unroll
  for (int j = 0; j < 4; ++j) {
    const int r = ty + j * 8;
    t[r][tx] = tof(s[(long long)(r0 + r) * ldsrc + c0 + tx]);
  }
  __syncthreads();
  #pragma unroll
  for (int j = 0; j < 4; ++j) {
    const int c = ty + j * 8;
    d[(long long)(c0 + c) * lddst + r0 + tx] = f2b(t[tx][c]);
  }
}

// ---------- stack bq|bk|bv per layer into (L,1536) ----------
__global__ __launch_bounds__(256) void biaspack_kernel(
    float* __restrict__ dst, const float* __restrict__ bq,
    const float* __restrict__ bk, const float* __restrict__ bv)
{
  const int i = blockIdx.x * 256 + threadIdx.x;
  if (i >= LL * 1536) return;
  const int l = i / 1536, j = i % 1536;
  dst[i] = (j < 512) ? bq[l * 512 + j]
         : (j < 1024) ? bk[l * 512 + j - 512]
                      : bv[l * 512 + j - 1024];
}

__global__ void finalize_loss(float* out) { out[0] = LAMBDA * (float)(LL * 32 * 1024); }

// ---------- host ----------
extern "C" void kernel_launch(void* const* d_in, const int* in_sizes, int n_in,
                              void* d_out, int out_size, void* d_ws, size_t ws_size,
                              hipStream_t stream)
{
  (void)in_sizes; (void)n_in; (void)out_size; (void)ws_size;
  const float* tok = (const float*)d_in[0];
  const float* pos = (const float*)d_in[1];
  const float* wq  = (const float*)d_in[2];
  const float* bq  = (const float*)d_in[3];
  const float* wk  = (const float*)d_in[4];
  const float* bk  = (const float*)d_in[5];
  const float* wv  = (const float*)d_in[6];
  const float* bv  = (const float*)d_in[7];
  const float* we  = (const float*)d_in[8];
  const float* be  = (const float*)d_in[9];
  const float* wd  = (const float*)d_in[10];
  const float* bd  = (const float*)d_in[11];
  const float* wo  = (const float*)d_in[12];
  const float* bo  = (const float*)d_in[13];
  const float* ln1g = (const float*)d_in[14];
  const float* ln1b = (const float*)d_in[15];
  const float* w1  = (const float*)d_in[16];
  const float* b1  = (const float*)d_in[17];
  const float* w2  = (const float*)d_in[18];
  const float* b2  = (const float*)d_in[19];
  const float* ln2g = (const float*)d_in[20];
  const float* ln2b = (const float*)d_in[21];
  const int*   x   = (const int*)d_in[22];

  char* ws = (char*)d_ws;
  size_t off = 0;
  auto alloc = [&](size_t bytes) { void* p = ws + off; off = (off + bytes + 255) & ~255ULL; return p; };

  u16*  wqkvT = (u16*)alloc((size_t)LL * 3 * 512 * 512 * 2);
  u16*  weT   = (u16*)alloc((size_t)LL * HH * T4 * TT * 2);
  u16*  wdT   = (u16*)alloc((size_t)LL * HH * TT * T4 * 2);
  u16*  woT   = (u16*)alloc((size_t)LL * EE * EE * 2);
  u16*  w1T   = (u16*)alloc((size_t)LL * FF * EE * 2);
  u16*  w2T   = (u16*)alloc((size_t)LL * EE * FF * 2);
  float* bqkv = (float*)alloc((size_t)LL * 1536 * 4);
  float* h_f  = (float*)alloc((size_t)BT * EE * 4);
  u16*  h_b   = (u16*)alloc((size_t)BT * EE * 2);
  u16*  qkv_b = (u16*)alloc((size_t)BT * 1536 * 2);
  u16*  kT_b  = (u16*)alloc((size_t)32 * HD * TT * 2);
  u16*  vT_b  = (u16*)alloc((size_t)32 * HD * TT * 2);
  u16*  MT_b  = (u16*)alloc((size_t)32 * T4 * HD * 2);
  u16*  lat_b = (u16*)alloc((size_t)32 * TT * T4 * 2);
  u16*  o_b   = (u16*)alloc((size_t)BT * EE * 2);
  float* attn_f = (float*)alloc((size_t)BT * EE * 4);
  float* ff2_f  = (float*)alloc((size_t)BT * EE * 4);
  u16*  ff1_b = (u16*)alloc((size_t)BT * FF * 2);

  const Off3 Z1 = {0, 0, 1};

  embed_kernel<<<dim3(BT), 256, 0, stream>>>(tok, pos, x, h_f, h_b);
  biaspack_kernel<<<dim3((LL * 1536 + 255) / 256), 256, 0, stream>>>(bqkv, bq, bk, bv);

  transposeT_kernel<float><<<dim3(16, 2, 48), 256, 0, stream>>>(
      wqkvT,          wq, 64, 512, Off3{786432, 32768, 8}, Off3{32768, 0, 1});
  transposeT_kernel<float><<<dim3(16, 2, 48), 256, 0, stream>>>(
      wqkvT + 262144, wk, 64, 512, Off3{786432, 32768, 8}, Off3{32768, 0, 1});
  transposeT_kernel<float><<<dim3(16, 2, 48), 256, 0, stream>>>(
      wqkvT + 524288, wv, 64, 512, Off3{786432, 32768, 8}, Off3{32768, 0, 1});
  transposeT_kernel<float><<<dim3(32, 8, 48), 256, 0, stream>>>(
      weT, we, 256, 1024, Off3{262144, 0, 1}, Off3{262144, 0, 1});
  transposeT_kernel<float><<<dim3(8, 32, 48), 256, 0, stream>>>(
      wdT, wd, 1024, 256, Off3{262144, 0, 1}, Off3{262144, 0, 1});
  transposeT_kernel<float><<<dim3(16, 16, 6), 256, 0, stream>>>(
      woT, wo, 512, 512, Off3{262144, 0, 1}, Off3{262144, 0, 1});
  transposeT_kernel<float><<<dim3(16, 64, 6), 256, 0, stream>>>(
      w1T, w1, 2048, 512, Off3{1048576, 0, 1}, Off3{1048576, 0, 1});
  transposeT_kernel<float><<<dim3(64, 16, 6), 256, 0, stream>>>(
      w2T, w2, 512, 2048, Off3{1048576, 0, 1}, Off3{1048576, 0, 1});

  for (int l = 0; l < LL; ++l) {
    // --- fused q|k|v projection ---
    gemm_bt<128, 128, true, 0><<<dim3(32, 12, 1), 256, 0, stream>>>(
        h_b, wqkvT + (size_t)l * 786432, qkv_b, bqkv + l * 1536, 1.0f,
        512, 512, 512, 1536, Z1, Z1, Z1, Z1);

    // k,v transposed per head: (bh, 64, 1024)
    transposeT_kernel<u16><<<dim3(32, 2, 32), 256, 0, stream>>>(
        kT_b, qkv_b + 512, 1536, 1024, Off3{65536, 0, 1}, Off3{1572864, 64, 8});
    transposeT_kernel<u16><<<dim3(32, 2, 32), 256, 0, stream>>>(
        vT_b, qkv_b + 1024, 1536, 1024, Off3{65536, 0, 1}, Off3{1572864, 64, 8});

    // --- MT[u][d] = sum_s we[s][u] k[s][d] ---
    gemm_bt<128, 64, true, 0><<<dim3(2, 1, 32), 256, 0, stream>>>(
        weT + (size_t)l * 2097152, kT_b, MT_b, nullptr, 1.0f,
        1024, 1024, 1024, 64,
        Off3{0, 262144, 8}, Off3{65536, 0, 1}, Off3{16384, 0, 1}, Z1);

    // --- lat = relu(0.125 * q @ MT^T + be) ---
    gemm_bt<128, 128, true, 1><<<dim3(8, 2, 32), 256, 0, stream>>>(
        qkv_b, MT_b, lat_b, be + l * 2048, 0.125f,
        64, 1536, 64, 256,
        Off3{1572864, 64, 8}, Off3{16384, 0, 1}, Off3{262144, 0, 1}, Off3{0, 256, 8});

    // --- fused: P = exp(sigmoid(lat@wd+bd)); o = (P/rowsum)@v ---
    attn_tail_kernel<<<dim3(16, 32), 256, 0, stream>>>(
        lat_b, wdT + (size_t)l * 2097152, bd + (size_t)l * 8192, vT_b, o_b);

    // --- attn out projection ---
    gemm_bt<128, 128, false, 0><<<dim3(32, 4, 1), 256, 0, stream>>>(
        o_b, woT + (size_t)l * 262144, attn_f, bo + l * 512, 1.0f,
        512, 512, 512, 512, Z1, Z1, Z1, Z1);

    addnorm_kernel<<<dim3(BT), 256, 0, stream>>>(h_f, attn_f, ln1g + l * 512, ln1b + l * 512, h_f, h_b);

    // --- FFN ---
    gemm_bt<128, 128, true, 1><<<dim3(32, 16, 1), 256, 0, stream>>>(
        h_b, w1T + (size_t)l * 1048576, ff1_b, b1 + l * 2048, 1.0f,
        512, 512, 512, 2048, Z1, Z1, Z1, Z1);
    gemm_bt<128, 128, false, 1><<<dim3(32, 4, 1), 256, 0, stream>>>(
        ff1_b, w2T + (size_t)l * 1048576, ff2_f, b2 + l * 512, 1.0f,
        2048, 2048, 2048, 512, Z1, Z1, Z1, Z1);

    float* hout = (l == LL - 1) ? (float*)d_out : h_f;
    addnorm_kernel<<<dim3(BT), 256, 0, stream>>>(h_f, ff2_f, ln2g + l * 512, ln2b + l * 512, hout, h_b);
  }

  finalize_loss<<<1, 1, 0, stream>>>((float*)d_out + (size_t)BT * EE);
}

// Round 5
// 1400.733 us; speedup vs baseline: 1.1620x; 1.1620x over previous
//
#include <hip/hip_runtime.h>

typedef unsigned short u16;
typedef __attribute__((ext_vector_type(8))) short short8;
typedef __attribute__((ext_vector_type(4))) float f32x4;
typedef const __attribute__((address_space(1))) void* gas_p;
typedef __attribute__((address_space(3))) void* las_p;

// ---------- constants ----------
#define LL (6)
#define BB (4)
#define TT (1024)
#define EE (512)
#define HH (8)
#define HD (64)
#define T4 (256)
#define FF (2048)
#define BT (BB*TT)           // 4096
#define LAMBDA (0.001f)

// ---------- helpers ----------
struct Off3 { long long hi, lo; int mod; };  // offset = (z/mod)*hi + (z%mod)*lo
__device__ __forceinline__ long long off3(Off3 o, int z) {
  return (long long)(z / o.mod) * o.hi + (long long)(z % o.mod) * o.lo;
}
__device__ __forceinline__ float b2f(u16 u) { return __uint_as_float((unsigned)u << 16); }
__device__ __forceinline__ u16 f2b(float f) {
  unsigned u = __float_as_uint(f);
  return (u16)((u + 0x7fffu + ((u >> 16) & 1u)) >> 16);   // RNE
}
__device__ __forceinline__ float tof(float v) { return v; }
__device__ __forceinline__ float tof(u16 v) { return b2f(v); }

// ---------- MFMA GEMM: C = act(alpha * A @ Bt^T + bias) ----------
// A: bf16 (M,K) lda; Bt: bf16 (N,K) ldb; C: f32/bf16 ldc. BK=32 fixed.
// ACT: 0=none 1=relu 3=exp(sigmoid(v))
template<int BM, int BN, bool C_BF16, int ACT>
__global__ __launch_bounds__(256) void gemm_bt(
    const u16* __restrict__ A, const u16* __restrict__ Bt, void* __restrict__ Cv,
    const float* __restrict__ bias, float alpha,
    int K, int lda, int ldb, int ldc,
    Off3 oa, Off3 ob, Off3 oc, Off3 obias)
{
  constexpr int WM = BM / 2, WN = BN / 2;
  constexpr int MR = WM / 16, NR = WN / 16;
  __shared__ alignas(16) u16 lA[BM * 32];
  __shared__ alignas(16) u16 lB[BN * 32];

  const int z = blockIdx.z;
  A  += off3(oa, z);
  Bt += off3(ob, z);
  const int tid = threadIdx.x;
  const int lane = tid & 63, wave = tid >> 6;
  const int wm = wave >> 1, wn = wave & 1;           // 2x2 wave grid
  const long long bm = (long long)blockIdx.x * BM;
  const long long bn = (long long)blockIdx.y * BN;

  f32x4 acc[MR][NR] = {};

  const int rsub = lane >> 2;          // 0..15 row within 16-row chunk
  const int segd = lane & 3;           // dest 16B segment within 64B row

  for (int k0 = 0; k0 < K; k0 += 32) {
    __syncthreads();
    #pragma unroll
    for (int j = 0; j < BM / 64; ++j) {
      const int i = wave * (BM / 64) + j;
      const int row = i * 16 + rsub;
      const int segs = segd ^ ((row >> 1) & 3);
      const u16* g = A + (bm + row) * (long long)lda + k0 + segs * 8;
      __builtin_amdgcn_global_load_lds((gas_p)g, (las_p)(lA + i * 512), 16, 0, 0);
    }
    #pragma unroll
    for (int j = 0; j < BN / 64; ++j) {
      const int i = wave * (BN / 64) + j;
      const int row = i * 16 + rsub;
      const int segs = segd ^ ((row >> 1) & 3);
      const u16* g = Bt + (bn + row) * (long long)ldb + k0 + segs * 8;
      __builtin_amdgcn_global_load_lds((gas_p)g, (las_p)(lB + i * 512), 16, 0, 0);
    }
    __syncthreads();

    const int seg = lane >> 4;
    short8 af[MR], bfr[NR];
    #pragma unroll
    for (int m = 0; m < MR; ++m) {
      const int row = wm * WM + m * 16 + (lane & 15);
      af[m] = *(const short8*)(lA + row * 32 + (seg ^ ((row >> 1) & 3)) * 8);
    }
    #pragma unroll
    for (int n = 0; n < NR; ++n) {
      const int row = wn * WN + n * 16 + (lane & 15);
      bfr[n] = *(const short8*)(lB + row * 32 + (seg ^ ((row >> 1) & 3)) * 8);
    }
    #pragma unroll
    for (int m = 0; m < MR; ++m)
      #pragma unroll
      for (int n = 0; n < NR; ++n)
        acc[m][n] = __builtin_amdgcn_mfma_f32_16x16x32_bf16(af[m], bfr[n], acc[m][n], 0, 0, 0);
  }

  const float* bp = bias ? (bias + off3(obias, z)) : nullptr;
  const long long cb = off3(oc, z);
  #pragma unroll
  for (int m = 0; m < MR; ++m) {
    const long long row0 = bm + wm * WM + m * 16 + (lane >> 4) * 4;
    #pragma unroll
    for (int n = 0; n < NR; ++n) {
      const long long col = bn + wn * WN + n * 16 + (lane & 15);
      const float bv = bp ? bp[col] : 0.0f;
      #pragma unroll
      for (int r = 0; r < 4; ++r) {
        float v = acc[m][n][r] * alpha + bv;
        if (ACT == 1) v = fmaxf(v, 0.0f);
        if (ACT == 3) v = __expf(1.0f / (1.0f + __expf(-v)));
        const long long idx = cb + (row0 + r) * (long long)ldc + col;
        if constexpr (C_BF16) ((u16*)Cv)[idx] = f2b(v);
        else                  ((float*)Cv)[idx] = v;
      }
    }
  }
}

// ---------- fused attention tail (v2: wave-per-16-t-rows, in-register P) ----------
// P[t,s] = exp(sigmoid(lat[t,:]·wd[:,s] + bd[s])); o[t,d] = (P/rowsum)·v[s,d]
// Transposed rec-MFMA: pacc = mfma(wd_frag, lat_frag) -> P^T frag:
//   per lane: col t = lane&15 (this wave's m-tile), row s_local = n*16 + g*4 + r.
// PV A-frag rebuilt in-register via cvt_pk + 4 shfl per 32-s chunk.
__global__ __launch_bounds__(256, 3) void attn_tail_kernel(
    const u16* __restrict__ lat, const u16* __restrict__ wdT,
    const float* __restrict__ bd, const u16* __restrict__ vT,
    u16* __restrict__ o)
{
  __shared__ alignas(16) u16 wdL[128 * 128];   // 32 KB: row=s(128), 128 u per kt
  __shared__ alignas(16) u16 vL[64 * 128];     // 16 KB: row=d(64), 128 s
  const int z = blockIdx.y, tb = blockIdx.x, h = z & 7;
  const int lane = threadIdx.x & 63, wave = threadIdx.x >> 6;
  const int g = lane >> 4;
  const u16* latz = lat + (size_t)z * 262144 + (size_t)tb * 64 * 256;
  const u16* wdh  = wdT + (size_t)h * 262144;
  const float* bdh = bd + (size_t)h * 1024;
  const u16* vz = vT + (size_t)z * 65536;

  // lat fragments: this wave's 16 t-rows (t_local = wave*16 + (lane&15)), k=u
  short8 af[8];
  {
    const u16* lp = latz + (size_t)(wave * 16 + (lane & 15)) * 256 + g * 8;
    #pragma unroll
    for (int kf = 0; kf < 8; ++kf) af[kf] = *(const short8*)(lp + kf * 32);
  }

  f32x4 oacc[4] = {};
  float rsum = 0.f;

  for (int sc = 0; sc < 8; ++sc) {
    f32x4 pacc[8] = {};
    #pragma unroll
    for (int kt = 0; kt < 2; ++kt) {
      __syncthreads();                       // prev reads of wdL/vL done
      #pragma unroll
      for (int j = 0; j < 8; ++j) {          // stage wd: 128 s-rows x 128 u
        const int i = wave * 8 + j;
        const int row = i * 4 + g;
        const int c16 = (lane & 15) ^ (row & 7);
        __builtin_amdgcn_global_load_lds(
            (gas_p)(wdh + (size_t)(sc * 128 + row) * 256 + kt * 128 + c16 * 8),
            (las_p)(wdL + i * 512), 16, 0, 0);
      }
      if (kt == 0) {
        #pragma unroll
        for (int j = 0; j < 4; ++j) {        // stage v: 64 d-rows x 128 s
          const int i = wave * 4 + j;
          const int row = i * 4 + g;
          const int c16 = (lane & 15) ^ (row & 7);
          __builtin_amdgcn_global_load_lds(
              (gas_p)(vz + (size_t)row * 1024 + sc * 128 + c16 * 8),
              (las_p)(vL + i * 512), 16, 0, 0);
        }
      }
      __syncthreads();                       // tiles visible
      #pragma unroll
      for (int kk = 0; kk < 4; ++kk) {
        #pragma unroll
        for (int n = 0; n < 8; ++n) {
          const int row = n * 16 + (lane & 15);
          const int gg = (kk * 4 + g) ^ (row & 7);
          const short8 bfr = *(const short8*)(wdL + row * 128 + gg * 8);
          pacc[n] = __builtin_amdgcn_mfma_f32_16x16x32_bf16(bfr, af[kt * 4 + kk], pacc[n], 0, 0, 0);
        }
      }
    }

    // epilogue: pe = exp(sigmoid(pacc + bd)); pack to bf16 pairs; rowsum
    unsigned wlo[8], whi[8];
    #pragma unroll
    for (int n = 0; n < 8; ++n) {
      const float4 b4 = *(const float4*)(bdh + sc * 128 + n * 16 + g * 4);
      float pe[4];
      #pragma unroll
      for (int r = 0; r < 4; ++r) {
        const float val = pacc[n][r] + ((const float*)&b4)[r];
        const float sig = 1.0f / (1.0f + __expf(-val));
        pe[r] = __expf(sig);
        rsum += pe[r];
      }
      asm("v_cvt_pk_bf16_f32 %0, %1, %2" : "=v"(wlo[n]) : "v"(pe[0]), "v"(pe[1]));
      asm("v_cvt_pk_bf16_f32 %0, %1, %2" : "=v"(whi[n]) : "v"(pe[2]), "v"(pe[3]));
    }

    // PV: rebuild A-frag (t=lane&15, k=s) from P^T pieces, 32 s per step
    #pragma unroll
    for (int ss = 0; ss < 4; ++ss) {
      const unsigned lo = (g & 2) ? wlo[2 * ss + 1] : wlo[2 * ss];
      const unsigned hi = (g & 2) ? whi[2 * ss + 1] : whi[2 * ss];
      const int src0 = (g & 1) * 32 + (lane & 15);
      short8 pa;
      ((unsigned*)&pa)[0] = (unsigned)__shfl((int)lo, src0);
      ((unsigned*)&pa)[1] = (unsigned)__shfl((int)hi, src0);
      ((unsigned*)&pa)[2] = (unsigned)__shfl((int)lo, src0 + 16);
      ((unsigned*)&pa)[3] = (unsigned)__shfl((int)hi, src0 + 16);
      #pragma unroll
      for (int nd = 0; nd < 4; ++nd) {
        const int d = nd * 16 + (lane & 15);
        const int gg = (ss * 4 + g) ^ (d & 7);
        const short8 vb = *(const short8*)(vL + d * 128 + gg * 8);
        oacc[nd] = __builtin_amdgcn_mfma_f32_16x16x32_bf16(pa, vb, oacc[nd], 0, 0, 0);
      }
    }
  }

  // full row sums (t = lane&15) and scaled store
  rsum += __shfl_xor(rsum, 16);
  rsum += __shfl_xor(rsum, 32);
  const long long orow0 = (long long)(z >> 3) * 1024 + tb * 64 + wave * 16;
  #pragma unroll
  for (int r = 0; r < 4; ++r) {
    const float inv = 1.0f / __shfl(rsum, g * 4 + r);
    #pragma unroll
    for (int nd = 0; nd < 4; ++nd)
      o[(orow0 + g * 4 + r) * 512 + (z & 7) * 64 + nd * 16 + (lane & 15)] =
          f2b(oacc[nd][r] * inv);
  }
}

// ---------- embedding: h = tok_emb[x] + pos_emb ----------
__global__ __launch_bounds__(256) void embed_kernel(
    const float* __restrict__ tok, const float* __restrict__ pos,
    const int* __restrict__ x, float* __restrict__ h, u16* __restrict__ hb)
{
  const long long row = blockIdx.x;
  const int t = (int)(row & (TT - 1));
  const long long tokid = x[row];
  const float* te = tok + tokid * EE;
  const float* pe = pos + (long long)t * EE;
  const long long base = row * EE;
  for (int e = threadIdx.x; e < EE; e += 256) {
    float v = te[e] + pe[e];
    h[base + e] = v;
    hb[base + e] = f2b(v);
  }
}

// ---------- residual + layernorm (row = 512) ----------
__global__ __launch_bounds__(256) void addnorm_kernel(
    const float* __restrict__ hin, const float* __restrict__ delta,
    const float* __restrict__ g, const float* __restrict__ bta,
    float* __restrict__ hout, u16* __restrict__ hbout)
{
  __shared__ float sm[8];
  const long long base = (long long)blockIdx.x * EE;
  const int tid = threadIdx.x;
  float x0 = hin[base + tid] + delta[base + tid];
  float x1 = hin[base + tid + 256] + delta[base + tid + 256];
  float s = x0 + x1, ss = x0 * x0 + x1 * x1;
  #pragma unroll
  for (int o = 32; o; o >>= 1) { s += __shfl_down(s, o); ss += __shfl_down(ss, o); }
  if ((tid & 63) == 0) { sm[tid >> 6] = s; sm[4 + (tid >> 6)] = ss; }
  __syncthreads();
  const float S = sm[0] + sm[1] + sm[2] + sm[3];
  const float SS = sm[4] + sm[5] + sm[6] + sm[7];
  const float mu = S * (1.0f / EE);
  const float var = SS * (1.0f / EE) - mu * mu;
  const float inv = rsqrtf(var + 1e-5f);
  const float y0 = (x0 - mu) * inv * g[tid] + bta[tid];
  const float y1 = (x1 - mu) * inv * g[tid + 256] + bta[tid + 256];
  hout[base + tid] = y0;       hout[base + tid + 256] = y1;
  hbout[base + tid] = f2b(y0); hbout[base + tid + 256] = f2b(y1);
}

// ---------- LDS-tiled transpose-convert: dst[z][c*lddst + r] = bf16(src[z][r*ldsrc + c]) ----------
template<typename ST>
__global__ __launch_bounds__(256) void transposeT_kernel(
    u16* __restrict__ dst, const ST* __restrict__ src,
    int ldsrc, int lddst, Off3 dstz, Off3 srcz)
{
  __shared__ float t[32][33];
  const int z = blockIdx.z;
  const ST* s = src + off3(srcz, z);
  u16* d = dst + off3(dstz, z);
  const int r0 = blockIdx.x * 32, c0 = blockIdx.y * 32;
  const int tx = threadIdx.x & 31, ty = threadIdx.x >> 5;
  #pragma unroll
  for (int j = 0; j < 4; ++j) {
    const int r = ty + j * 8;
    t[r][tx] = tof(s[(long long)(r0 + r) * ldsrc + c0 + tx]);
  }
  __syncthreads();
  #pragma unroll
  for (int j = 0; j < 4; ++j) {
    const int c = ty + j * 8;
    d[(long long)(c0 + c) * lddst + r0 + tx] = f2b(t[tx][c]);
  }
}

// ---------- stack bq|bk|bv per layer into (L,1536) ----------
__global__ __launch_bounds__(256) void biaspack_kernel(
    float* __restrict__ dst, const float* __restrict__ bq,
    const float* __restrict__ bk, const float* __restrict__ bv)
{
  const int i = blockIdx.x * 256 + threadIdx.x;
  if (i >= LL * 1536) return;
  const int l = i / 1536, j = i % 1536;
  dst[i] = (j < 512) ? bq[l * 512 + j]
         : (j < 1024) ? bk[l * 512 + j - 512]
                      : bv[l * 512 + j - 1024];
}

__global__ void finalize_loss(float* out) { out[0] = LAMBDA * (float)(LL * 32 * 1024); }

// ---------- host ----------
extern "C" void kernel_launch(void* const* d_in, const int* in_sizes, int n_in,
                              void* d_out, int out_size, void* d_ws, size_t ws_size,
                              hipStream_t stream)
{
  (void)in_sizes; (void)n_in; (void)out_size; (void)ws_size;
  const float* tok = (const float*)d_in[0];
  const float* pos = (const float*)d_in[1];
  const float* wq  = (const float*)d_in[2];
  const float* bq  = (const float*)d_in[3];
  const float* wk  = (const float*)d_in[4];
  const float* bk  = (const float*)d_in[5];
  const float* wv  = (const float*)d_in[6];
  const float* bv  = (const float*)d_in[7];
  const float* we  = (const float*)d_in[8];
  const float* be  = (const float*)d_in[9];
  const float* wd  = (const float*)d_in[10];
  const float* bd  = (const float*)d_in[11];
  const float* wo  = (const float*)d_in[12];
  const float* bo  = (const float*)d_in[13];
  const float* ln1g = (const float*)d_in[14];
  const float* ln1b = (const float*)d_in[15];
  const float* w1  = (const float*)d_in[16];
  const float* b1  = (const float*)d_in[17];
  const float* w2  = (const float*)d_in[18];
  const float* b2  = (const float*)d_in[19];
  const float* ln2g = (const float*)d_in[20];
  const float* ln2b = (const float*)d_in[21];
  const int*   x   = (const int*)d_in[22];

  char* ws = (char*)d_ws;
  size_t off = 0;
  auto alloc = [&](size_t bytes) { void* p = ws + off; off = (off + bytes + 255) & ~255ULL; return p; };

  u16*  wqkvT = (u16*)alloc((size_t)LL * 3 * 512 * 512 * 2);
  u16*  weT   = (u16*)alloc((size_t)LL * HH * T4 * TT * 2);
  u16*  wdT   = (u16*)alloc((size_t)LL * HH * TT * T4 * 2);
  u16*  woT   = (u16*)alloc((size_t)LL * EE * EE * 2);
  u16*  w1T   = (u16*)alloc((size_t)LL * FF * EE * 2);
  u16*  w2T   = (u16*)alloc((size_t)LL * EE * FF * 2);
  float* bqkv = (float*)alloc((size_t)LL * 1536 * 4);
  float* h_f  = (float*)alloc((size_t)BT * EE * 4);
  u16*  h_b   = (u16*)alloc((size_t)BT * EE * 2);
  u16*  qkv_b = (u16*)alloc((size_t)BT * 1536 * 2);
  u16*  kT_b  = (u16*)alloc((size_t)32 * HD * TT * 2);
  u16*  vT_b  = (u16*)alloc((size_t)32 * HD * TT * 2);
  u16*  MT_b  = (u16*)alloc((size_t)32 * T4 * HD * 2);
  u16*  lat_b = (u16*)alloc((size_t)32 * TT * T4 * 2);
  u16*  o_b   = (u16*)alloc((size_t)BT * EE * 2);
  float* attn_f = (float*)alloc((size_t)BT * EE * 4);
  float* ff2_f  = (float*)alloc((size_t)BT * EE * 4);
  u16*  ff1_b = (u16*)alloc((size_t)BT * FF * 2);

  const Off3 Z1 = {0, 0, 1};

  embed_kernel<<<dim3(BT), 256, 0, stream>>>(tok, pos, x, h_f, h_b);
  biaspack_kernel<<<dim3((LL * 1536 + 255) / 256), 256, 0, stream>>>(bqkv, bq, bk, bv);

  transposeT_kernel<float><<<dim3(16, 2, 48), 256, 0, stream>>>(
      wqkvT,          wq, 64, 512, Off3{786432, 32768, 8}, Off3{32768, 0, 1});
  transposeT_kernel<float><<<dim3(16, 2, 48), 256, 0, stream>>>(
      wqkvT + 262144, wk, 64, 512, Off3{786432, 32768, 8}, Off3{32768, 0, 1});
  transposeT_kernel<float><<<dim3(16, 2, 48), 256, 0, stream>>>(
      wqkvT + 524288, wv, 64, 512, Off3{786432, 32768, 8}, Off3{32768, 0, 1});
  transposeT_kernel<float><<<dim3(32, 8, 48), 256, 0, stream>>>(
      weT, we, 256, 1024, Off3{262144, 0, 1}, Off3{262144, 0, 1});
  transposeT_kernel<float><<<dim3(8, 32, 48), 256, 0, stream>>>(
      wdT, wd, 1024, 256, Off3{262144, 0, 1}, Off3{262144, 0, 1});
  transposeT_kernel<float><<<dim3(16, 16, 6), 256, 0, stream>>>(
      woT, wo, 512, 512, Off3{262144, 0, 1}, Off3{262144, 0, 1});
  transposeT_kernel<float><<<dim3(16, 64, 6), 256, 0, stream>>>(
      w1T, w1, 2048, 512, Off3{1048576, 0, 1}, Off3{1048576, 0, 1});
  transposeT_kernel<float><<<dim3(64, 16, 6), 256, 0, stream>>>(
      w2T, w2, 512, 2048, Off3{1048576, 0, 1}, Off3{1048576, 0, 1});

  for (int l = 0; l < LL; ++l) {
    // --- fused q|k|v projection ---
    gemm_bt<128, 128, true, 0><<<dim3(32, 12, 1), 256, 0, stream>>>(
        h_b, wqkvT + (size_t)l * 786432, qkv_b, bqkv + l * 1536, 1.0f,
        512, 512, 512, 1536, Z1, Z1, Z1, Z1);

    // k,v transposed per head: (bh, 64, 1024)
    transposeT_kernel<u16><<<dim3(32, 2, 32), 256, 0, stream>>>(
        kT_b, qkv_b + 512, 1536, 1024, Off3{65536, 0, 1}, Off3{1572864, 64, 8});
    transposeT_kernel<u16><<<dim3(32, 2, 32), 256, 0, stream>>>(
        vT_b, qkv_b + 1024, 1536, 1024, Off3{65536, 0, 1}, Off3{1572864, 64, 8});

    // --- MT[u][d] = sum_s we[s][u] k[s][d] ---
    gemm_bt<64, 64, true, 0><<<dim3(4, 1, 32), 256, 0, stream>>>(
        weT + (size_t)l * 2097152, kT_b, MT_b, nullptr, 1.0f,
        1024, 1024, 1024, 64,
        Off3{0, 262144, 8}, Off3{65536, 0, 1}, Off3{16384, 0, 1}, Z1);

    // --- lat = relu(0.125 * q @ MT^T + be) ---
    gemm_bt<128, 128, true, 1><<<dim3(8, 2, 32), 256, 0, stream>>>(
        qkv_b, MT_b, lat_b, be + l * 2048, 0.125f,
        64, 1536, 64, 256,
        Off3{1572864, 64, 8}, Off3{16384, 0, 1}, Off3{262144, 0, 1}, Off3{0, 256, 8});

    // --- fused: P = exp(sigmoid(lat@wd+bd)); o = (P/rowsum)@v ---
    attn_tail_kernel<<<dim3(16, 32), 256, 0, stream>>>(
        lat_b, wdT + (size_t)l * 2097152, bd + (size_t)l * 8192, vT_b, o_b);

    // --- attn out projection ---
    gemm_bt<128, 128, false, 0><<<dim3(32, 4, 1), 256, 0, stream>>>(
        o_b, woT + (size_t)l * 262144, attn_f, bo + l * 512, 1.0f,
        512, 512, 512, 512, Z1, Z1, Z1, Z1);

    addnorm_kernel<<<dim3(BT), 256, 0, stream>>>(h_f, attn_f, ln1g + l * 512, ln1b + l * 512, h_f, h_b);

    // --- FFN ---
    gemm_bt<128, 128, true, 1><<<dim3(32, 16, 1), 256, 0, stream>>>(
        h_b, w1T + (size_t)l * 1048576, ff1_b, b1 + l * 2048, 1.0f,
        512, 512, 512, 2048, Z1, Z1, Z1, Z1);
    gemm_bt<128, 128, false, 1><<<dim3(32, 4, 1), 256, 0, stream>>>(
        ff1_b, w2T + (size_t)l * 1048576, ff2_f, b2 + l * 512, 1.0f,
        2048, 2048, 2048, 512, Z1, Z1, Z1, Z1);

    float* hout = (l == LL - 1) ? (float*)d_out : h_f;
    addnorm_kernel<<<dim3(BT), 256, 0, stream>>>(h_f, ff2_f, ln2g + l * 512, ln2b + l * 512, hout, h_b);
  }

  finalize_loss<<<1, 1, 0, stream>>>((float*)d_out + (size_t)BT * EE);
}

// Round 6
// 1326.900 us; speedup vs baseline: 1.2266x; 1.0556x over previous
//
#include <hip/hip_runtime.h>

typedef unsigned short u16;
typedef __attribute__((ext_vector_type(8))) short short8;
typedef __attribute__((ext_vector_type(4))) float f32x4;
typedef const __attribute__((address_space(1))) void* gas_p;
typedef __attribute__((address_space(3))) void* las_p;

// ---------- constants ----------
#define LL (6)
#define BB (4)
#define TT (1024)
#define EE (512)
#define HH (8)
#define HD (64)
#define T4 (256)
#define FF (2048)
#define BT (BB*TT)           // 4096
#define LAMBDA (0.001f)

// ---------- helpers ----------
struct Off3 { long long hi, lo; int mod; };  // offset = (z/mod)*hi + (z%mod)*lo
__device__ __forceinline__ long long off3(Off3 o, int z) {
  return (long long)(z / o.mod) * o.hi + (long long)(z % o.mod) * o.lo;
}
__device__ __forceinline__ float b2f(u16 u) { return __uint_as_float((unsigned)u << 16); }
__device__ __forceinline__ u16 f2b(float f) {
  unsigned u = __float_as_uint(f);
  return (u16)((u + 0x7fffu + ((u >> 16) & 1u)) >> 16);   // RNE
}
__device__ __forceinline__ float tof(float v) { return v; }
__device__ __forceinline__ float tof(u16 v) { return b2f(v); }

// ---------- MFMA GEMM: C = act(alpha * A @ Bt^T + bias) ----------
// A: bf16 (M,K) lda; Bt: bf16 (N,K) ldb; C: f32/bf16 ldc. BK=32 fixed.
// ACT: 0=none 1=relu
template<int BM, int BN, bool C_BF16, int ACT>
__global__ __launch_bounds__(256) void gemm_bt(
    const u16* __restrict__ A, const u16* __restrict__ Bt, void* __restrict__ Cv,
    const float* __restrict__ bias, float alpha,
    int K, int lda, int ldb, int ldc,
    Off3 oa, Off3 ob, Off3 oc, Off3 obias)
{
  constexpr int WM = BM / 2, WN = BN / 2;
  constexpr int MR = WM / 16, NR = WN / 16;
  __shared__ alignas(16) u16 lA[BM * 32];
  __shared__ alignas(16) u16 lB[BN * 32];

  const int z = blockIdx.z;
  A  += off3(oa, z);
  Bt += off3(ob, z);
  const int tid = threadIdx.x;
  const int lane = tid & 63, wave = tid >> 6;
  const int wm = wave >> 1, wn = wave & 1;           // 2x2 wave grid
  const long long bm = (long long)blockIdx.x * BM;
  const long long bn = (long long)blockIdx.y * BN;

  f32x4 acc[MR][NR] = {};

  const int rsub = lane >> 2;          // 0..15 row within 16-row chunk
  const int segd = lane & 3;           // dest 16B segment within 64B row

  for (int k0 = 0; k0 < K; k0 += 32) {
    __syncthreads();
    #pragma unroll
    for (int j = 0; j < BM / 64; ++j) {
      const int i = wave * (BM / 64) + j;
      const int row = i * 16 + rsub;
      const int segs = segd ^ ((row >> 1) & 3);
      const u16* g = A + (bm + row) * (long long)lda + k0 + segs * 8;
      __builtin_amdgcn_global_load_lds((gas_p)g, (las_p)(lA + i * 512), 16, 0, 0);
    }
    #pragma unroll
    for (int j = 0; j < BN / 64; ++j) {
      const int i = wave * (BN / 64) + j;
      const int row = i * 16 + rsub;
      const int segs = segd ^ ((row >> 1) & 3);
      const u16* g = Bt + (bn + row) * (long long)ldb + k0 + segs * 8;
      __builtin_amdgcn_global_load_lds((gas_p)g, (las_p)(lB + i * 512), 16, 0, 0);
    }
    __syncthreads();

    const int seg = lane >> 4;
    short8 af[MR], bfr[NR];
    #pragma unroll
    for (int m = 0; m < MR; ++m) {
      const int row = wm * WM + m * 16 + (lane & 15);
      af[m] = *(const short8*)(lA + row * 32 + (seg ^ ((row >> 1) & 3)) * 8);
    }
    #pragma unroll
    for (int n = 0; n < NR; ++n) {
      const int row = wn * WN + n * 16 + (lane & 15);
      bfr[n] = *(const short8*)(lB + row * 32 + (seg ^ ((row >> 1) & 3)) * 8);
    }
    #pragma unroll
    for (int m = 0; m < MR; ++m)
      #pragma unroll
      for (int n = 0; n < NR; ++n)
        acc[m][n] = __builtin_amdgcn_mfma_f32_16x16x32_bf16(af[m], bfr[n], acc[m][n], 0, 0, 0);
  }

  const float* bp = bias ? (bias + off3(obias, z)) : nullptr;
  const long long cb = off3(oc, z);
  #pragma unroll
  for (int m = 0; m < MR; ++m) {
    const long long row0 = bm + wm * WM + m * 16 + (lane >> 4) * 4;
    #pragma unroll
    for (int n = 0; n < NR; ++n) {
      const long long col = bn + wn * WN + n * 16 + (lane & 15);
      const float bv = bp ? bp[col] : 0.0f;
      #pragma unroll
      for (int r = 0; r < 4; ++r) {
        float v = acc[m][n][r] * alpha + bv;
        if (ACT == 1) v = fmaxf(v, 0.0f);
        const long long idx = cb + (row0 + r) * (long long)ldc + col;
        if constexpr (C_BF16) ((u16*)Cv)[idx] = f2b(v);
        else                  ((float*)Cv)[idx] = v;
      }
    }
  }
}

// ---------- fused attention tail (v3: s-split, small working set, clean swizzle) ----------
// block (tb, sp, z): 64 t-rows, s in [sp*512, sp*512+512). Per sc: 64 s, full u=256.
// P^T via mfma(wd_frag, lat_frag); PV A-frag rebuilt in-register via cvt_pk + shfl.
// Outputs: o_part f32 (per sp), rs_part f32 (per sp).
__global__ __launch_bounds__(256, 4) void attn_tail_kernel(
    const u16* __restrict__ lat, const u16* __restrict__ wdT,
    const float* __restrict__ bd, const u16* __restrict__ vT,
    float* __restrict__ o_part, float* __restrict__ rs_part)
{
  __shared__ alignas(16) u16 wdL[64 * 256];   // 32 KB: [s:64][u:256], 512B rows
  __shared__ alignas(16) u16 vL[64 * 64];     // 8 KB : [d:64][s:64], 128B rows
  const int z = blockIdx.z, sp = blockIdx.y, tb = blockIdx.x, h = z & 7;
  const int lane = threadIdx.x & 63, wave = threadIdx.x >> 6;
  const int g = lane >> 4, l15 = lane & 15;
  const int s0 = sp * 512;
  const u16* latz = lat + (size_t)z * 262144 + (size_t)tb * 64 * 256;
  const u16* wdh  = wdT + (size_t)h * 262144;
  const float* bdh = bd + (size_t)h * 1024 + s0;
  const u16* vz = vT + (size_t)z * 65536 + s0;

  // lat fragments: wave owns t_local = wave*16 + l15; k = u (8 x 32)
  short8 af[8];
  {
    const u16* lp = latz + (size_t)(wave * 16 + l15) * 256 + g * 8;
    #pragma unroll
    for (int kf = 0; kf < 8; ++kf) af[kf] = *(const short8*)(lp + kf * 32);
  }

  f32x4 oacc[4] = {};
  float rsum = 0.f;

  for (int sc = 0; sc < 8; ++sc) {
    const int sbase = sc * 64;
    __syncthreads();                            // prev phase reads done
    // stage wd [64 s][256 u]: 2048 x 16B chunks, slot ^= (row&7)
    #pragma unroll
    for (int j = 0; j < 8; ++j) {
      const int cbase = j * 256 + wave * 64;
      const int c = cbase + lane;
      const int row = c >> 5, slot = c & 31;
      const int sl = slot ^ (row & 7);
      __builtin_amdgcn_global_load_lds(
          (gas_p)(wdh + (size_t)(s0 + sbase + row) * 256 + sl * 8),
          (las_p)(wdL + cbase * 8), 16, 0, 0);
    }
    // stage v [64 d][64 s]: 512 x 16B chunks
    #pragma unroll
    for (int j = 0; j < 2; ++j) {
      const int cbase = j * 256 + wave * 64;
      const int c = cbase + lane;
      const int row = c >> 3, slot = c & 7;
      const int sl = slot ^ (row & 7);
      __builtin_amdgcn_global_load_lds(
          (gas_p)(vz + (size_t)row * 1024 + sbase + sl * 8),
          (las_p)(vL + cbase * 8), 16, 0, 0);
    }
    __syncthreads();                            // tiles visible

    // rec: pacc[n] = P^T fragment, s_local = n*16 + g*4 + r, t = l15
    f32x4 pacc[4] = {};
    #pragma unroll
    for (int kk = 0; kk < 8; ++kk) {
      #pragma unroll
      for (int n = 0; n < 4; ++n) {
        const int row = n * 16 + l15;
        const int sl = (kk * 4 + g) ^ (row & 7);
        const short8 bfr = *(const short8*)(wdL + row * 256 + sl * 8);
        pacc[n] = __builtin_amdgcn_mfma_f32_16x16x32_bf16(bfr, af[kk], pacc[n], 0, 0, 0);
      }
    }

    // epilogue: pe = exp(sigmoid(pacc + bd)); pack bf16 pairs; rowsum partial
    unsigned wlo[4], whi[4];
    #pragma unroll
    for (int n = 0; n < 4; ++n) {
      const float4 b4 = *(const float4*)(bdh + sbase + n * 16 + g * 4);
      float pe[4];
      #pragma unroll
      for (int r = 0; r < 4; ++r) {
        const float val = pacc[n][r] + ((const float*)&b4)[r];
        const float sig = 1.0f / (1.0f + __expf(-val));
        pe[r] = __expf(sig);
        rsum += pe[r];
      }
      asm("v_cvt_pk_bf16_f32 %0, %1, %2" : "=v"(wlo[n]) : "v"(pe[0]), "v"(pe[1]));
      asm("v_cvt_pk_bf16_f32 %0, %1, %2" : "=v"(whi[n]) : "v"(pe[2]), "v"(pe[3]));
    }

    // PV: rebuild A-frag (t=l15, k=s_local) from P^T pieces, 32 s per step
    #pragma unroll
    for (int ss = 0; ss < 2; ++ss) {
      const unsigned lo = (g & 2) ? wlo[2 * ss + 1] : wlo[2 * ss];
      const unsigned hi = (g & 2) ? whi[2 * ss + 1] : whi[2 * ss];
      const int src0 = (g & 1) * 32 + l15;
      short8 pa;
      ((unsigned*)&pa)[0] = (unsigned)__shfl((int)lo, src0);
      ((unsigned*)&pa)[1] = (unsigned)__shfl((int)hi, src0);
      ((unsigned*)&pa)[2] = (unsigned)__shfl((int)lo, src0 + 16);
      ((unsigned*)&pa)[3] = (unsigned)__shfl((int)hi, src0 + 16);
      #pragma unroll
      for (int nd = 0; nd < 4; ++nd) {
        const int d = nd * 16 + l15;
        const int sl = (ss * 4 + g) ^ (d & 7);
        const short8 vb = *(const short8*)(vL + d * 64 + sl * 8);
        oacc[nd] = __builtin_amdgcn_mfma_f32_16x16x32_bf16(pa, vb, oacc[nd], 0, 0, 0);
      }
    }
  }

  // partial row sums (replicate over g), store partials
  rsum += __shfl_xor(rsum, 16);
  rsum += __shfl_xor(rsum, 32);
  const long long orow0 = (long long)(z >> 3) * 1024 + tb * 64 + wave * 16;
  float* op = o_part + (size_t)sp * ((size_t)BT * EE);
  #pragma unroll
  for (int r = 0; r < 4; ++r) {
    #pragma unroll
    for (int nd = 0; nd < 4; ++nd)
      op[(orow0 + g * 4 + r) * 512 + (z & 7) * 64 + nd * 16 + l15] = oacc[nd][r];
  }
  if (g == 0)
    rs_part[(size_t)sp * 32768 + (size_t)z * 1024 + tb * 64 + wave * 16 + l15] = rsum;
}

// ---------- combine partials: o = (o0+o1) / (rs0+rs1), bf16 ----------
__global__ __launch_bounds__(256) void attn_combine_kernel(
    const float* __restrict__ o_part, const float* __restrict__ rs_part,
    u16* __restrict__ o)
{
  const int row = blockIdx.x;                 // 4096
  const int b = row >> 10, t = row & 1023;
  #pragma unroll
  for (int j = 0; j < 2; ++j) {
    const int c = j * 256 + threadIdx.x;
    const int bh = b * 8 + (c >> 6);
    const float rs = rs_part[(size_t)bh * 1024 + t] + rs_part[32768 + (size_t)bh * 1024 + t];
    const float v = (o_part[(size_t)row * 512 + c] +
                     o_part[(size_t)BT * EE + (size_t)row * 512 + c]) / rs;
    o[(size_t)row * 512 + c] = f2b(v);
  }
}

// ---------- embedding: h = tok_emb[x] + pos_emb ----------
__global__ __launch_bounds__(256) void embed_kernel(
    const float* __restrict__ tok, const float* __restrict__ pos,
    const int* __restrict__ x, float* __restrict__ h, u16* __restrict__ hb)
{
  const long long row = blockIdx.x;
  const int t = (int)(row & (TT - 1));
  const long long tokid = x[row];
  const float* te = tok + tokid * EE;
  const float* pe = pos + (long long)t * EE;
  const long long base = row * EE;
  for (int e = threadIdx.x; e < EE; e += 256) {
    float v = te[e] + pe[e];
    h[base + e] = v;
    hb[base + e] = f2b(v);
  }
}

// ---------- residual + layernorm (row = 512) ----------
__global__ __launch_bounds__(256) void addnorm_kernel(
    const float* __restrict__ hin, const float* __restrict__ delta,
    const float* __restrict__ g, const float* __restrict__ bta,
    float* __restrict__ hout, u16* __restrict__ hbout)
{
  __shared__ float sm[8];
  const long long base = (long long)blockIdx.x * EE;
  const int tid = threadIdx.x;
  float x0 = hin[base + tid] + delta[base + tid];
  float x1 = hin[base + tid + 256] + delta[base + tid + 256];
  float s = x0 + x1, ss = x0 * x0 + x1 * x1;
  #pragma unroll
  for (int o = 32; o; o >>= 1) { s += __shfl_down(s, o); ss += __shfl_down(ss, o); }
  if ((tid & 63) == 0) { sm[tid >> 6] = s; sm[4 + (tid >> 6)] = ss; }
  __syncthreads();
  const float S = sm[0] + sm[1] + sm[2] + sm[3];
  const float SS = sm[4] + sm[5] + sm[6] + sm[7];
  const float mu = S * (1.0f / EE);
  const float var = SS * (1.0f / EE) - mu * mu;
  const float inv = rsqrtf(var + 1e-5f);
  const float y0 = (x0 - mu) * inv * g[tid] + bta[tid];
  const float y1 = (x1 - mu) * inv * g[tid + 256] + bta[tid + 256];
  hout[base + tid] = y0;       hout[base + tid + 256] = y1;
  hbout[base + tid] = f2b(y0); hbout[base + tid + 256] = f2b(y1);
}

// ---------- LDS-tiled transpose-convert: dst[z][c*lddst + r] = bf16(src[z][r*ldsrc + c]) ----------
template<typename ST>
__global__ __launch_bounds__(256) void transposeT_kernel(
    u16* __restrict__ dst, const ST* __restrict__ src,
    int ldsrc, int lddst, Off3 dstz, Off3 srcz)
{
  __shared__ float t[32][33];
  const int z = blockIdx.z;
  const ST* s = src + off3(srcz, z);
  u16* d = dst + off3(dstz, z);
  const int r0 = blockIdx.x * 32, c0 = blockIdx.y * 32;
  const int tx = threadIdx.x & 31, ty = threadIdx.x >> 5;
  #pragma unroll
  for (int j = 0; j < 4; ++j) {
    const int r = ty + j * 8;
    t[r][tx] = tof(s[(long long)(r0 + r) * ldsrc + c0 + tx]);
  }
  __syncthreads();
  #pragma unroll
  for (int j = 0; j < 4; ++j) {
    const int c = ty + j * 8;
    d[(long long)(c0 + c) * lddst + r0 + tx] = f2b(t[tx][c]);
  }
}

// ---------- stack bq|bk|bv per layer into (L,1536) ----------
__global__ __launch_bounds__(256) void biaspack_kernel(
    float* __restrict__ dst, const float* __restrict__ bq,
    const float* __restrict__ bk, const float* __restrict__ bv)
{
  const int i = blockIdx.x * 256 + threadIdx.x;
  if (i >= LL * 1536) return;
  const int l = i / 1536, j = i % 1536;
  dst[i] = (j < 512) ? bq[l * 512 + j]
         : (j < 1024) ? bk[l * 512 + j - 512]
                      : bv[l * 512 + j - 1024];
}

__global__ void finalize_loss(float* out) { out[0] = LAMBDA * (float)(LL * 32 * 1024); }

// ---------- host ----------
extern "C" void kernel_launch(void* const* d_in, const int* in_sizes, int n_in,
                              void* d_out, int out_size, void* d_ws, size_t ws_size,
                              hipStream_t stream)
{
  (void)in_sizes; (void)n_in; (void)out_size; (void)ws_size;
  const float* tok = (const float*)d_in[0];
  const float* pos = (const float*)d_in[1];
  const float* wq  = (const float*)d_in[2];
  const float* bq  = (const float*)d_in[3];
  const float* wk  = (const float*)d_in[4];
  const float* bk  = (const float*)d_in[5];
  const float* wv  = (const float*)d_in[6];
  const float* bv  = (const float*)d_in[7];
  const float* we  = (const float*)d_in[8];
  const float* be  = (const float*)d_in[9];
  const float* wd  = (const float*)d_in[10];
  const float* bd  = (const float*)d_in[11];
  const float* wo  = (const float*)d_in[12];
  const float* bo  = (const float*)d_in[13];
  const float* ln1g = (const float*)d_in[14];
  const float* ln1b = (const float*)d_in[15];
  const float* w1  = (const float*)d_in[16];
  const float* b1  = (const float*)d_in[17];
  const float* w2  = (const float*)d_in[18];
  const float* b2  = (const float*)d_in[19];
  const float* ln2g = (const float*)d_in[20];
  const float* ln2b = (const float*)d_in[21];
  const int*   x   = (const int*)d_in[22];

  char* ws = (char*)d_ws;
  size_t off = 0;
  auto alloc = [&](size_t bytes) { void* p = ws + off; off = (off + bytes + 255) & ~255ULL; return p; };

  u16*  wqkvT = (u16*)alloc((size_t)LL * 3 * 512 * 512 * 2);
  u16*  weT   = (u16*)alloc((size_t)LL * HH * T4 * TT * 2);
  u16*  wdT   = (u16*)alloc((size_t)LL * HH * TT * T4 * 2);
  u16*  woT   = (u16*)alloc((size_t)LL * EE * EE * 2);
  u16*  w1T   = (u16*)alloc((size_t)LL * FF * EE * 2);
  u16*  w2T   = (u16*)alloc((size_t)LL * EE * FF * 2);
  float* bqkv = (float*)alloc((size_t)LL * 1536 * 4);
  float* h_f  = (float*)alloc((size_t)BT * EE * 4);
  u16*  h_b   = (u16*)alloc((size_t)BT * EE * 2);
  u16*  qkv_b = (u16*)alloc((size_t)BT * 1536 * 2);
  u16*  kT_b  = (u16*)alloc((size_t)32 * HD * TT * 2);
  u16*  vT_b  = (u16*)alloc((size_t)32 * HD * TT * 2);
  u16*  MT_b  = (u16*)alloc((size_t)32 * T4 * HD * 2);
  u16*  lat_b = (u16*)alloc((size_t)32 * TT * T4 * 2);
  u16*  o_b   = (u16*)alloc((size_t)BT * EE * 2);
  float* attn_f = (float*)alloc((size_t)BT * EE * 4);
  float* ff2_f  = (float*)alloc((size_t)BT * EE * 4);
  u16*  ff1_b = (u16*)alloc((size_t)BT * FF * 2);
  float* o_part = (float*)alloc((size_t)2 * BT * EE * 4);
  float* rs_part = (float*)alloc((size_t)2 * 32 * 1024 * 4);

  const Off3 Z1 = {0, 0, 1};

  embed_kernel<<<dim3(BT), 256, 0, stream>>>(tok, pos, x, h_f, h_b);
  biaspack_kernel<<<dim3((LL * 1536 + 255) / 256), 256, 0, stream>>>(bqkv, bq, bk, bv);

  transposeT_kernel<float><<<dim3(16, 2, 48), 256, 0, stream>>>(
      wqkvT,          wq, 64, 512, Off3{786432, 32768, 8}, Off3{32768, 0, 1});
  transposeT_kernel<float><<<dim3(16, 2, 48), 256, 0, stream>>>(
      wqkvT + 262144, wk, 64, 512, Off3{786432, 32768, 8}, Off3{32768, 0, 1});
  transposeT_kernel<float><<<dim3(16, 2, 48), 256, 0, stream>>>(
      wqkvT + 524288, wv, 64, 512, Off3{786432, 32768, 8}, Off3{32768, 0, 1});
  transposeT_kernel<float><<<dim3(32, 8, 48), 256, 0, stream>>>(
      weT, we, 256, 1024, Off3{262144, 0, 1}, Off3{262144, 0, 1});
  transposeT_kernel<float><<<dim3(8, 32, 48), 256, 0, stream>>>(
      wdT, wd, 1024, 256, Off3{262144, 0, 1}, Off3{262144, 0, 1});
  transposeT_kernel<float><<<dim3(16, 16, 6), 256, 0, stream>>>(
      woT, wo, 512, 512, Off3{262144, 0, 1}, Off3{262144, 0, 1});
  transposeT_kernel<float><<<dim3(16, 64, 6), 256, 0, stream>>>(
      w1T, w1, 2048, 512, Off3{1048576, 0, 1}, Off3{1048576, 0, 1});
  transposeT_kernel<float><<<dim3(64, 16, 6), 256, 0, stream>>>(
      w2T, w2, 512, 2048, Off3{1048576, 0, 1}, Off3{1048576, 0, 1});

  for (int l = 0; l < LL; ++l) {
    // --- fused q|k|v projection ---
    gemm_bt<128, 128, true, 0><<<dim3(32, 12, 1), 256, 0, stream>>>(
        h_b, wqkvT + (size_t)l * 786432, qkv_b, bqkv + l * 1536, 1.0f,
        512, 512, 512, 1536, Z1, Z1, Z1, Z1);

    // k,v transposed per head: (bh, 64, 1024)
    transposeT_kernel<u16><<<dim3(32, 2, 32), 256, 0, stream>>>(
        kT_b, qkv_b + 512, 1536, 1024, Off3{65536, 0, 1}, Off3{1572864, 64, 8});
    transposeT_kernel<u16><<<dim3(32, 2, 32), 256, 0, stream>>>(
        vT_b, qkv_b + 1024, 1536, 1024, Off3{65536, 0, 1}, Off3{1572864, 64, 8});

    // --- MT[u][d] = sum_s we[s][u] k[s][d] ---
    gemm_bt<64, 64, true, 0><<<dim3(4, 1, 32), 256, 0, stream>>>(
        weT + (size_t)l * 2097152, kT_b, MT_b, nullptr, 1.0f,
        1024, 1024, 1024, 64,
        Off3{0, 262144, 8}, Off3{65536, 0, 1}, Off3{16384, 0, 1}, Z1);

    // --- lat = relu(0.125 * q @ MT^T + be) ---
    gemm_bt<128, 128, true, 1><<<dim3(8, 2, 32), 256, 0, stream>>>(
        qkv_b, MT_b, lat_b, be + l * 2048, 0.125f,
        64, 1536, 64, 256,
        Off3{1572864, 64, 8}, Off3{16384, 0, 1}, Off3{262144, 0, 1}, Off3{0, 256, 8});

    // --- fused: P = exp(sigmoid(lat@wd+bd)); partial O and rowsum per s-half ---
    attn_tail_kernel<<<dim3(16, 2, 32), 256, 0, stream>>>(
        lat_b, wdT + (size_t)l * 2097152, bd + (size_t)l * 8192, vT_b, o_part, rs_part);
    attn_combine_kernel<<<dim3(BT), 256, 0, stream>>>(o_part, rs_part, o_b);

    // --- attn out projection ---
    gemm_bt<128, 128, false, 0><<<dim3(32, 4, 1), 256, 0, stream>>>(
        o_b, woT + (size_t)l * 262144, attn_f, bo + l * 512, 1.0f,
        512, 512, 512, 512, Z1, Z1, Z1, Z1);

    addnorm_kernel<<<dim3(BT), 256, 0, stream>>>(h_f, attn_f, ln1g + l * 512, ln1b + l * 512, h_f, h_b);

    // --- FFN ---
    gemm_bt<128, 128, true, 1><<<dim3(32, 16, 1), 256, 0, stream>>>(
        h_b, w1T + (size_t)l * 1048576, ff1_b, b1 + l * 2048, 1.0f,
        512, 512, 512, 2048, Z1, Z1, Z1, Z1);
    gemm_bt<128, 128, false, 1><<<dim3(32, 4, 1), 256, 0, stream>>>(
        ff1_b, w2T + (size_t)l * 1048576, ff2_f, b2 + l * 512, 1.0f,
        2048, 2048, 2048, 512, Z1, Z1, Z1, Z1);

    float* hout = (l == LL - 1) ? (float*)d_out : h_f;
    addnorm_kernel<<<dim3(BT), 256, 0, stream>>>(h_f, ff2_f, ln2g + l * 512, ln2b + l * 512, hout, h_b);
  }

  finalize_loss<<<1, 1, 0, stream>>>((float*)d_out + (size_t)BT * EE);
}

// Round 7
// 1058.014 us; speedup vs baseline: 1.5384x; 1.2541x over previous
//
#include <hip/hip_runtime.h>

typedef unsigned short u16;
typedef __attribute__((ext_vector_type(8))) short short8;
typedef __attribute__((ext_vector_type(4))) float f32x4;
typedef const __attribute__((address_space(1))) void* gas_p;
typedef __attribute__((address_space(3))) void* las_p;

// ---------- constants ----------
#define LL (6)
#define BB (4)
#define TT (1024)
#define EE (512)
#define HH (8)
#define HD (64)
#define T4 (256)
#define FF (2048)
#define BT (BB*TT)           // 4096
#define LAMBDA (0.001f)

// ---------- helpers ----------
struct Off3 { long long hi, lo; int mod; };  // offset = (z/mod)*hi + (z%mod)*lo
__device__ __forceinline__ long long off3(Off3 o, int z) {
  return (long long)(z / o.mod) * o.hi + (long long)(z % o.mod) * o.lo;
}
__device__ __forceinline__ float b2f(u16 u) { return __uint_as_float((unsigned)u << 16); }
__device__ __forceinline__ u16 f2b(float f) {
  unsigned u = __float_as_uint(f);
  return (u16)((u + 0x7fffu + ((u >> 16) & 1u)) >> 16);   // RNE
}
__device__ __forceinline__ float tof(float v) { return v; }
__device__ __forceinline__ float tof(u16 v) { return b2f(v); }

// ---------- pipelined MFMA GEMM: C = act(alpha * A @ Bt^T + bias) ----------
// A: bf16 (M,K) lda; Bt: bf16 (N,K) ldb. BK=64, double-buffered LDS:
//   stage(next) issued BEFORE compute(cur); one barrier per K-step (T3-lite).
// LDS rows = 64 u16 = 8 x 16B slots, slot ^= (row&7) on source & read.
// ACT: 0=none 1=relu. SPLITK: blockIdx.y = k-split (bn=0), f32 partial out.
template<int BM, int BN, bool C_BF16, int ACT, bool SPLITK>
__global__ __launch_bounds__(256) void gemm_p(
    const u16* __restrict__ A, const u16* __restrict__ Bt, void* __restrict__ Cv,
    const float* __restrict__ bias, float alpha,
    int K, int lda, int ldb, int ldc,
    Off3 oa, Off3 ob, Off3 oc, Off3 obias, long long sstride)
{
  constexpr int BK = 64;
  constexpr int WM = BM / 2, WN = BN / 2;
  constexpr int MR = WM / 16, NR = WN / 16;
  __shared__ alignas(16) u16 lA[2][BM * BK];
  __shared__ alignas(16) u16 lB[2][BN * BK];

  const int z = blockIdx.z;
  A  += off3(oa, z);
  Bt += off3(ob, z);
  long long cb = off3(oc, z);
  long long bn;
  if constexpr (SPLITK) {
    const long long kb = (long long)blockIdx.y * K;
    A += kb; Bt += kb;
    cb += (long long)blockIdx.y * sstride;
    bn = 0;
  } else {
    bn = (long long)blockIdx.y * BN;
  }
  const int tid = threadIdx.x;
  const int lane = tid & 63, wave = tid >> 6;
  const int wm = wave >> 1, wn = wave & 1;           // 2x2 wave grid
  const int l15 = lane & 15, g = lane >> 4;
  const long long bm = (long long)blockIdx.x * BM;

#define STAGE(buf, k0)                                                          \
  {                                                                             \
    _Pragma("unroll")                                                           \
    for (int j = 0; j < (BM * 8) / 256; ++j) {                                  \
      const int c = j * 256 + tid, row = c >> 3, slot = c & 7;                  \
      const u16* src = A + (bm + row) * (long long)lda + (k0) +                 \
                       ((slot ^ (row & 7)) << 3);                               \
      __builtin_amdgcn_global_load_lds((gas_p)src, (las_p)(&lA[buf][c * 8]), 16, 0, 0); \
    }                                                                           \
    _Pragma("unroll")                                                           \
    for (int j = 0; j < (BN * 8) / 256; ++j) {                                  \
      const int c = j * 256 + tid, row = c >> 3, slot = c & 7;                  \
      const u16* src = Bt + (bn + row) * (long long)ldb + (k0) +                \
                       ((slot ^ (row & 7)) << 3);                               \
      __builtin_amdgcn_global_load_lds((gas_p)src, (las_p)(&lB[buf][c * 8]), 16, 0, 0); \
    }                                                                           \
  }

  f32x4 acc[MR][NR] = {};
  STAGE(0, 0);
  __syncthreads();
  int cur = 0;
  for (int k0 = 0; k0 < K; k0 += BK) {
    if (k0 + BK < K) STAGE(cur ^ 1, k0 + BK);      // prefetch next tile
    #pragma unroll
    for (int kk = 0; kk < 2; ++kk) {
      short8 af[MR], bfr[NR];
      #pragma unroll
      for (int m = 0; m < MR; ++m) {
        const int row = wm * WM + m * 16 + l15;
        af[m] = *(const short8*)(&lA[cur][row * BK + ((((kk << 2) + g) ^ (row & 7)) << 3)]);
      }
      #pragma unroll
      for (int n = 0; n < NR; ++n) {
        const int row = wn * WN + n * 16 + l15;
        bfr[n] = *(const short8*)(&lB[cur][row * BK + ((((kk << 2) + g) ^ (row & 7)) << 3)]);
      }
      #pragma unroll
      for (int m = 0; m < MR; ++m)
        #pragma unroll
        for (int n = 0; n < NR; ++n)
          acc[m][n] = __builtin_amdgcn_mfma_f32_16x16x32_bf16(af[m], bfr[n], acc[m][n], 0, 0, 0);
    }
    __syncthreads();                               // drain prefetch + reads
    cur ^= 1;
  }
#undef STAGE

  const float* bp = bias ? (bias + off3(obias, z)) : nullptr;
  #pragma unroll
  for (int m = 0; m < MR; ++m) {
    const long long row0 = bm + wm * WM + m * 16 + g * 4;
    #pragma unroll
    for (int n = 0; n < NR; ++n) {
      const long long col = bn + wn * WN + n * 16 + l15;
      const float bv = bp ? bp[col] : 0.0f;
      #pragma unroll
      for (int r = 0; r < 4; ++r) {
        float v = acc[m][n][r] * alpha + bv;
        if (ACT == 1) v = fmaxf(v, 0.0f);
        const long long idx = cb + (row0 + r) * (long long)ldc + col;
        if constexpr (C_BF16) ((u16*)Cv)[idx] = f2b(v);
        else                  ((float*)Cv)[idx] = v;
      }
    }
  }
}

// ---------- sum 4 split-K partials -> bf16 ----------
__global__ __launch_bounds__(256) void mt_combine_kernel(
    const float* __restrict__ part, u16* __restrict__ out)
{
  const int i = blockIdx.x * 256 + threadIdx.x;     // 524288
  const float s = part[i] + part[i + 524288] + part[i + 2 * 524288] + part[i + 3 * 524288];
  out[i] = f2b(s);
}

// ---------- fused attention tail (v3: s-split, small working set) ----------
__global__ __launch_bounds__(256, 4) void attn_tail_kernel(
    const u16* __restrict__ lat, const u16* __restrict__ wdT,
    const float* __restrict__ bd, const u16* __restrict__ vT,
    float* __restrict__ o_part, float* __restrict__ rs_part)
{
  __shared__ alignas(16) u16 wdL[64 * 256];   // 32 KB: [s:64][u:256]
  __shared__ alignas(16) u16 vL[64 * 64];     // 8 KB : [d:64][s:64]
  const int z = blockIdx.z, sp = blockIdx.y, tb = blockIdx.x, h = z & 7;
  const int lane = threadIdx.x & 63, wave = threadIdx.x >> 6;
  const int g = lane >> 4, l15 = lane & 15;
  const int s0 = sp * 512;
  const u16* latz = lat + (size_t)z * 262144 + (size_t)tb * 64 * 256;
  const u16* wdh  = wdT + (size_t)h * 262144;
  const float* bdh = bd + (size_t)h * 1024 + s0;
  const u16* vz = vT + (size_t)z * 65536 + s0;

  short8 af[8];
  {
    const u16* lp = latz + (size_t)(wave * 16 + l15) * 256 + g * 8;
    #pragma unroll
    for (int kf = 0; kf < 8; ++kf) af[kf] = *(const short8*)(lp + kf * 32);
  }

  f32x4 oacc[4] = {};
  float rsum = 0.f;

  for (int sc = 0; sc < 8; ++sc) {
    const int sbase = sc * 64;
    __syncthreads();
    #pragma unroll
    for (int j = 0; j < 8; ++j) {
      const int cbase = j * 256 + wave * 64;
      const int c = cbase + lane;
      const int row = c >> 5, slot = c & 31;
      const int sl = slot ^ (row & 7);
      __builtin_amdgcn_global_load_lds(
          (gas_p)(wdh + (size_t)(s0 + sbase + row) * 256 + sl * 8),
          (las_p)(wdL + cbase * 8), 16, 0, 0);
    }
    #pragma unroll
    for (int j = 0; j < 2; ++j) {
      const int cbase = j * 256 + wave * 64;
      const int c = cbase + lane;
      const int row = c >> 3, slot = c & 7;
      const int sl = slot ^ (row & 7);
      __builtin_amdgcn_global_load_lds(
          (gas_p)(vz + (size_t)row * 1024 + sbase + sl * 8),
          (las_p)(vL + cbase * 8), 16, 0, 0);
    }
    __syncthreads();

    f32x4 pacc[4] = {};
    #pragma unroll
    for (int kk = 0; kk < 8; ++kk) {
      #pragma unroll
      for (int n = 0; n < 4; ++n) {
        const int row = n * 16 + l15;
        const int sl = (kk * 4 + g) ^ (row & 7);
        const short8 bfr = *(const short8*)(wdL + row * 256 + sl * 8);
        pacc[n] = __builtin_amdgcn_mfma_f32_16x16x32_bf16(bfr, af[kk], pacc[n], 0, 0, 0);
      }
    }

    unsigned wlo[4], whi[4];
    #pragma unroll
    for (int n = 0; n < 4; ++n) {
      const float4 b4 = *(const float4*)(bdh + sbase + n * 16 + g * 4);
      float pe[4];
      #pragma unroll
      for (int r = 0; r < 4; ++r) {
        const float val = pacc[n][r] + ((const float*)&b4)[r];
        const float sig = 1.0f / (1.0f + __expf(-val));
        pe[r] = __expf(sig);
        rsum += pe[r];
      }
      asm("v_cvt_pk_bf16_f32 %0, %1, %2" : "=v"(wlo[n]) : "v"(pe[0]), "v"(pe[1]));
      asm("v_cvt_pk_bf16_f32 %0, %1, %2" : "=v"(whi[n]) : "v"(pe[2]), "v"(pe[3]));
    }

    #pragma unroll
    for (int ss = 0; ss < 2; ++ss) {
      const unsigned lo = (g & 2) ? wlo[2 * ss + 1] : wlo[2 * ss];
      const unsigned hi = (g & 2) ? whi[2 * ss + 1] : whi[2 * ss];
      const int src0 = (g & 1) * 32 + l15;
      short8 pa;
      ((unsigned*)&pa)[0] = (unsigned)__shfl((int)lo, src0);
      ((unsigned*)&pa)[1] = (unsigned)__shfl((int)hi, src0);
      ((unsigned*)&pa)[2] = (unsigned)__shfl((int)lo, src0 + 16);
      ((unsigned*)&pa)[3] = (unsigned)__shfl((int)hi, src0 + 16);
      #pragma unroll
      for (int nd = 0; nd < 4; ++nd) {
        const int d = nd * 16 + l15;
        const int sl = (ss * 4 + g) ^ (d & 7);
        const short8 vb = *(const short8*)(vL + d * 64 + sl * 8);
        oacc[nd] = __builtin_amdgcn_mfma_f32_16x16x32_bf16(pa, vb, oacc[nd], 0, 0, 0);
      }
    }
  }

  rsum += __shfl_xor(rsum, 16);
  rsum += __shfl_xor(rsum, 32);
  const long long orow0 = (long long)(z >> 3) * 1024 + tb * 64 + wave * 16;
  float* op = o_part + (size_t)sp * ((size_t)BT * EE);
  #pragma unroll
  for (int r = 0; r < 4; ++r) {
    #pragma unroll
    for (int nd = 0; nd < 4; ++nd)
      op[(orow0 + g * 4 + r) * 512 + (z & 7) * 64 + nd * 16 + l15] = oacc[nd][r];
  }
  if (g == 0)
    rs_part[(size_t)sp * 32768 + (size_t)z * 1024 + tb * 64 + wave * 16 + l15] = rsum;
}

// ---------- combine partials: o = (o0+o1) / (rs0+rs1), bf16 ----------
__global__ __launch_bounds__(256) void attn_combine_kernel(
    const float* __restrict__ o_part, const float* __restrict__ rs_part,
    u16* __restrict__ o)
{
  const int row = blockIdx.x;                 // 4096
  const int b = row >> 10, t = row & 1023;
  #pragma unroll
  for (int j = 0; j < 2; ++j) {
    const int c = j * 256 + threadIdx.x;
    const int bh = b * 8 + (c >> 6);
    const float rs = rs_part[(size_t)bh * 1024 + t] + rs_part[32768 + (size_t)bh * 1024 + t];
    const float v = (o_part[(size_t)row * 512 + c] +
                     o_part[(size_t)BT * EE + (size_t)row * 512 + c]) / rs;
    o[(size_t)row * 512 + c] = f2b(v);
  }
}

// ---------- embedding: h = tok_emb[x] + pos_emb ----------
__global__ __launch_bounds__(256) void embed_kernel(
    const float* __restrict__ tok, const float* __restrict__ pos,
    const int* __restrict__ x, float* __restrict__ h, u16* __restrict__ hb)
{
  const long long row = blockIdx.x;
  const int t = (int)(row & (TT - 1));
  const long long tokid = x[row];
  const float* te = tok + tokid * EE;
  const float* pe = pos + (long long)t * EE;
  const long long base = row * EE;
  for (int e = threadIdx.x; e < EE; e += 256) {
    float v = te[e] + pe[e];
    h[base + e] = v;
    hb[base + e] = f2b(v);
  }
}

// ---------- residual + layernorm (row = 512), bf16 delta ----------
__global__ __launch_bounds__(256) void addnorm_kernel(
    const float* __restrict__ hin, const u16* __restrict__ delta,
    const float* __restrict__ g, const float* __restrict__ bta,
    float* __restrict__ hout, u16* __restrict__ hbout)
{
  __shared__ float sm[8];
  const long long base = (long long)blockIdx.x * EE;
  const int tid = threadIdx.x;
  float x0 = hin[base + tid] + b2f(delta[base + tid]);
  float x1 = hin[base + tid + 256] + b2f(delta[base + tid + 256]);
  float s = x0 + x1, ss = x0 * x0 + x1 * x1;
  #pragma unroll
  for (int o = 32; o; o >>= 1) { s += __shfl_down(s, o); ss += __shfl_down(ss, o); }
  if ((tid & 63) == 0) { sm[tid >> 6] = s; sm[4 + (tid >> 6)] = ss; }
  __syncthreads();
  const float S = sm[0] + sm[1] + sm[2] + sm[3];
  const float SS = sm[4] + sm[5] + sm[6] + sm[7];
  const float mu = S * (1.0f / EE);
  const float var = SS * (1.0f / EE) - mu * mu;
  const float inv = rsqrtf(var + 1e-5f);
  const float y0 = (x0 - mu) * inv * g[tid] + bta[tid];
  const float y1 = (x1 - mu) * inv * g[tid + 256] + bta[tid + 256];
  hout[base + tid] = y0;       hout[base + tid + 256] = y1;
  hbout[base + tid] = f2b(y0); hbout[base + tid + 256] = f2b(y1);
}

// ---------- LDS-tiled transpose-convert ----------
template<typename ST>
__global__ __launch_bounds__(256) void transposeT_kernel(
    u16* __restrict__ dst, const ST* __restrict__ src,
    int ldsrc, int lddst, Off3 dstz, Off3 srcz)
{
  __shared__ float t[32][33];
  const int z = blockIdx.z;
  const ST* s = src + off3(srcz, z);
  u16* d = dst + off3(dstz, z);
  const int r0 = blockIdx.x * 32, c0 = blockIdx.y * 32;
  const int tx = threadIdx.x & 31, ty = threadIdx.x >> 5;
  #pragma unroll
  for (int j = 0; j < 4; ++j) {
    const int r = ty + j * 8;
    t[r][tx] = tof(s[(long long)(r0 + r) * ldsrc + c0 + tx]);
  }
  __syncthreads();
  #pragma unroll
  for (int j = 0; j < 4; ++j) {
    const int c = ty + j * 8;
    d[(long long)(c0 + c) * lddst + r0 + tx] = f2b(t[tx][c]);
  }
}

// ---------- stack bq|bk|bv per layer into (L,1536) ----------
__global__ __launch_bounds__(256) void biaspack_kernel(
    float* __restrict__ dst, const float* __restrict__ bq,
    const float* __restrict__ bk, const float* __restrict__ bv)
{
  const int i = blockIdx.x * 256 + threadIdx.x;
  if (i >= LL * 1536) return;
  const int l = i / 1536, j = i % 1536;
  dst[i] = (j < 512) ? bq[l * 512 + j]
         : (j < 1024) ? bk[l * 512 + j - 512]
                      : bv[l * 512 + j - 1024];
}

__global__ void finalize_loss(float* out) { out[0] = LAMBDA * (float)(LL * 32 * 1024); }

// ---------- host ----------
extern "C" void kernel_launch(void* const* d_in, const int* in_sizes, int n_in,
                              void* d_out, int out_size, void* d_ws, size_t ws_size,
                              hipStream_t stream)
{
  (void)in_sizes; (void)n_in; (void)out_size; (void)ws_size;
  const float* tok = (const float*)d_in[0];
  const float* pos = (const float*)d_in[1];
  const float* wq  = (const float*)d_in[2];
  const float* bq  = (const float*)d_in[3];
  const float* wk  = (const float*)d_in[4];
  const float* bk  = (const float*)d_in[5];
  const float* wv  = (const float*)d_in[6];
  const float* bv  = (const float*)d_in[7];
  const float* we  = (const float*)d_in[8];
  const float* be  = (const float*)d_in[9];
  const float* wd  = (const float*)d_in[10];
  const float* bd  = (const float*)d_in[11];
  const float* wo  = (const float*)d_in[12];
  const float* bo  = (const float*)d_in[13];
  const float* ln1g = (const float*)d_in[14];
  const float* ln1b = (const float*)d_in[15];
  const float* w1  = (const float*)d_in[16];
  const float* b1  = (const float*)d_in[17];
  const float* w2  = (const float*)d_in[18];
  const float* b2  = (const float*)d_in[19];
  const float* ln2g = (const float*)d_in[20];
  const float* ln2b = (const float*)d_in[21];
  const int*   x   = (const int*)d_in[22];

  char* ws = (char*)d_ws;
  size_t off = 0;
  auto alloc = [&](size_t bytes) { void* p = ws + off; off = (off + bytes + 255) & ~255ULL; return p; };

  u16*  wqkvT = (u16*)alloc((size_t)LL * 3 * 512 * 512 * 2);
  u16*  weT   = (u16*)alloc((size_t)LL * HH * T4 * TT * 2);
  u16*  wdT   = (u16*)alloc((size_t)LL * HH * TT * T4 * 2);
  u16*  woT   = (u16*)alloc((size_t)LL * EE * EE * 2);
  u16*  w1T   = (u16*)alloc((size_t)LL * FF * EE * 2);
  u16*  w2T   = (u16*)alloc((size_t)LL * EE * FF * 2);
  float* bqkv = (float*)alloc((size_t)LL * 1536 * 4);
  float* h_f  = (float*)alloc((size_t)BT * EE * 4);
  u16*  h_b   = (u16*)alloc((size_t)BT * EE * 2);
  u16*  qkv_b = (u16*)alloc((size_t)BT * 1536 * 2);
  u16*  kT_b  = (u16*)alloc((size_t)32 * HD * TT * 2);
  u16*  vT_b  = (u16*)alloc((size_t)32 * HD * TT * 2);
  u16*  MT_b  = (u16*)alloc((size_t)32 * T4 * HD * 2);
  float* MT_part = (float*)alloc((size_t)4 * 32 * T4 * HD * 4);   // 8 MB
  u16*  lat_b = (u16*)alloc((size_t)32 * TT * T4 * 2);
  u16*  o_b   = (u16*)alloc((size_t)BT * EE * 2);
  u16*  attn_d = (u16*)alloc((size_t)BT * EE * 2);
  u16*  ff2_d  = (u16*)alloc((size_t)BT * EE * 2);
  u16*  ff1_b = (u16*)alloc((size_t)BT * FF * 2);
  float* o_part = (float*)alloc((size_t)2 * BT * EE * 4);
  float* rs_part = (float*)alloc((size_t)2 * 32 * 1024 * 4);

  const Off3 Z1 = {0, 0, 1};

  embed_kernel<<<dim3(BT), 256, 0, stream>>>(tok, pos, x, h_f, h_b);
  biaspack_kernel<<<dim3((LL * 1536 + 255) / 256), 256, 0, stream>>>(bqkv, bq, bk, bv);

  transposeT_kernel<float><<<dim3(16, 2, 48), 256, 0, stream>>>(
      wqkvT,          wq, 64, 512, Off3{786432, 32768, 8}, Off3{32768, 0, 1});
  transposeT_kernel<float><<<dim3(16, 2, 48), 256, 0, stream>>>(
      wqkvT + 262144, wk, 64, 512, Off3{786432, 32768, 8}, Off3{32768, 0, 1});
  transposeT_kernel<float><<<dim3(16, 2, 48), 256, 0, stream>>>(
      wqkvT + 524288, wv, 64, 512, Off3{786432, 32768, 8}, Off3{32768, 0, 1});
  transposeT_kernel<float><<<dim3(32, 8, 48), 256, 0, stream>>>(
      weT, we, 256, 1024, Off3{262144, 0, 1}, Off3{262144, 0, 1});
  transposeT_kernel<float><<<dim3(8, 32, 48), 256, 0, stream>>>(
      wdT, wd, 1024, 256, Off3{262144, 0, 1}, Off3{262144, 0, 1});
  transposeT_kernel<float><<<dim3(16, 16, 6), 256, 0, stream>>>(
      woT, wo, 512, 512, Off3{262144, 0, 1}, Off3{262144, 0, 1});
  transposeT_kernel<float><<<dim3(16, 64, 6), 256, 0, stream>>>(
      w1T, w1, 2048, 512, Off3{1048576, 0, 1}, Off3{1048576, 0, 1});
  transposeT_kernel<float><<<dim3(64, 16, 6), 256, 0, stream>>>(
      w2T, w2, 512, 2048, Off3{1048576, 0, 1}, Off3{1048576, 0, 1});

  for (int l = 0; l < LL; ++l) {
    // --- fused q|k|v projection: (4096,1536,512), 768 blocks ---
    gemm_p<64, 128, true, 0, false><<<dim3(64, 12, 1), 256, 0, stream>>>(
        h_b, wqkvT + (size_t)l * 786432, qkv_b, bqkv + l * 1536, 1.0f,
        512, 512, 512, 1536, Z1, Z1, Z1, Z1, 0);

    // k,v transposed per head: (bh, 64, 1024)
    transposeT_kernel<u16><<<dim3(32, 2, 32), 256, 0, stream>>>(
        kT_b, qkv_b + 512, 1536, 1024, Off3{65536, 0, 1}, Off3{1572864, 64, 8});
    transposeT_kernel<u16><<<dim3(32, 2, 32), 256, 0, stream>>>(
        vT_b, qkv_b + 1024, 1536, 1024, Off3{65536, 0, 1}, Off3{1572864, 64, 8});

    // --- MT[u][d] = sum_s we[s][u] k[s][d] : split-K x4, 512 blocks ---
    gemm_p<64, 64, false, 0, true><<<dim3(4, 4, 32), 256, 0, stream>>>(
        weT + (size_t)l * 2097152, kT_b, MT_part, nullptr, 1.0f,
        256, 1024, 1024, 64,
        Off3{0, 262144, 8}, Off3{65536, 0, 1}, Off3{16384, 0, 1}, Z1, 524288);
    mt_combine_kernel<<<dim3(2048), 256, 0, stream>>>(MT_part, MT_b);

    // --- lat = relu(0.125 * q @ MT^T + be) : 1024 blocks ---
    gemm_p<64, 128, true, 1, false><<<dim3(16, 2, 32), 256, 0, stream>>>(
        qkv_b, MT_b, lat_b, be + l * 2048, 0.125f,
        64, 1536, 64, 256,
        Off3{1572864, 64, 8}, Off3{16384, 0, 1}, Off3{262144, 0, 1}, Off3{0, 256, 8}, 0);

    // --- fused: P = exp(sigmoid(lat@wd+bd)); partial O and rowsum per s-half ---
    attn_tail_kernel<<<dim3(16, 2, 32), 256, 0, stream>>>(
        lat_b, wdT + (size_t)l * 2097152, bd + (size_t)l * 8192, vT_b, o_part, rs_part);
    attn_combine_kernel<<<dim3(BT), 256, 0, stream>>>(o_part, rs_part, o_b);

    // --- attn out projection: 512 blocks, bf16 out ---
    gemm_p<64, 64, true, 0, false><<<dim3(64, 8, 1), 256, 0, stream>>>(
        o_b, woT + (size_t)l * 262144, attn_d, bo + l * 512, 1.0f,
        512, 512, 512, 512, Z1, Z1, Z1, Z1, 0);

    addnorm_kernel<<<dim3(BT), 256, 0, stream>>>(h_f, attn_d, ln1g + l * 512, ln1b + l * 512, h_f, h_b);

    // --- FFN: ff1 1024 blocks, ff2 512 blocks ---
    gemm_p<64, 128, true, 1, false><<<dim3(64, 16, 1), 256, 0, stream>>>(
        h_b, w1T + (size_t)l * 1048576, ff1_b, b1 + l * 2048, 1.0f,
        512, 512, 512, 2048, Z1, Z1, Z1, Z1, 0);
    gemm_p<64, 64, true, 1, false><<<dim3(64, 8, 1), 256, 0, stream>>>(
        ff1_b, w2T + (size_t)l * 1048576, ff2_d, b2 + l * 512, 1.0f,
        2048, 2048, 2048, 512, Z1, Z1, Z1, Z1, 0);

    float* hout = (l == LL - 1) ? (float*)d_out : h_f;
    addnorm_kernel<<<dim3(BT), 256, 0, stream>>>(h_f, ff2_d, ln2g + l * 512, ln2b + l * 512, hout, h_b);
  }

  finalize_loss<<<1, 1, 0, stream>>>((float*)d_out + (size_t)BT * EE);
}

// Round 8
// 1023.441 us; speedup vs baseline: 1.5904x; 1.0338x over previous
//
#include <hip/hip_runtime.h>

typedef unsigned short u16;
typedef __attribute__((ext_vector_type(8))) short short8;
typedef __attribute__((ext_vector_type(4))) float f32x4;
typedef __attribute__((ext_vector_type(16))) float f32x16;
typedef const __attribute__((address_space(1))) void* gas_p;
typedef __attribute__((address_space(3))) void* las_p;

// ---------- constants ----------
#define LL (6)
#define BB (4)
#define TT (1024)
#define EE (512)
#define HH (8)
#define HD (64)
#define T4 (256)
#define FF (2048)
#define BT (BB*TT)           // 4096
#define LAMBDA (0.001f)

// ---------- helpers ----------
struct Off3 { long long hi, lo; int mod; };
__device__ __forceinline__ long long off3(Off3 o, int z) {
  return (long long)(z / o.mod) * o.hi + (long long)(z % o.mod) * o.lo;
}
__device__ __forceinline__ float b2f(u16 u) { return __uint_as_float((unsigned)u << 16); }
__device__ __forceinline__ u16 f2b(float f) {
  unsigned u = __float_as_uint(f);
  return (u16)((u + 0x7fffu + ((u >> 16) & 1u)) >> 16);   // RNE
}
__device__ __forceinline__ float tof(float v) { return v; }
__device__ __forceinline__ float tof(u16 v) { return b2f(v); }

// ---------- pipelined MFMA GEMM: C = act(alpha * A @ Bt^T + bias) ----------
// BK=64, double-buffered LDS; stage(next) before compute(cur); 1 barrier/K-step.
// QKV mode: N=1536 cols = q|k|v; q written row-major, k/v written transposed
// per head into kTo/vTo (ushort4 along t).
template<int BM, int BN, bool C_BF16, int ACT, bool SPLITK, bool QKV>
__global__ __launch_bounds__(256) void gemm_p(
    const u16* __restrict__ A, const u16* __restrict__ Bt, void* __restrict__ Cv,
    const float* __restrict__ bias, float alpha,
    int K, int lda, int ldb, int ldc,
    Off3 oa, Off3 ob, Off3 oc, Off3 obias, long long sstride,
    u16* __restrict__ kTo, u16* __restrict__ vTo)
{
  constexpr int BK = 64;
  constexpr int WM = BM / 2, WN = BN / 2;
  constexpr int MR = WM / 16, NR = WN / 16;
  __shared__ alignas(16) u16 lA[2][BM * BK];
  __shared__ alignas(16) u16 lB[2][BN * BK];

  const int z = blockIdx.z;
  A  += off3(oa, z);
  Bt += off3(ob, z);
  long long cb = off3(oc, z);
  long long bn;
  if constexpr (SPLITK) {
    const long long kb = (long long)blockIdx.y * K;
    A += kb; Bt += kb;
    cb += (long long)blockIdx.y * sstride;
    bn = 0;
  } else {
    bn = (long long)blockIdx.y * BN;
  }
  const int tid = threadIdx.x;
  const int lane = tid & 63, wave = tid >> 6;
  const int wm = wave >> 1, wn = wave & 1;
  const int l15 = lane & 15, g = lane >> 4;
  const long long bm = (long long)blockIdx.x * BM;

#define STAGE(buf, k0)                                                          \
  {                                                                             \
    _Pragma("unroll")                                                           \
    for (int j = 0; j < (BM * 8) / 256; ++j) {                                  \
      const int c = j * 256 + tid, row = c >> 3, slot = c & 7;                  \
      const u16* src = A + (bm + row) * (long long)lda + (k0) +                 \
                       ((slot ^ (row & 7)) << 3);                               \
      __builtin_amdgcn_global_load_lds((gas_p)src, (las_p)(&lA[buf][c * 8]), 16, 0, 0); \
    }                                                                           \
    _Pragma("unroll")                                                           \
    for (int j = 0; j < (BN * 8) / 256; ++j) {                                  \
      const int c = j * 256 + tid, row = c >> 3, slot = c & 7;                  \
      const u16* src = Bt + (bn + row) * (long long)ldb + (k0) +                \
                       ((slot ^ (row & 7)) << 3);                               \
      __builtin_amdgcn_global_load_lds((gas_p)src, (las_p)(&lB[buf][c * 8]), 16, 0, 0); \
    }                                                                           \
  }

  f32x4 acc[MR][NR] = {};
  STAGE(0, 0);
  __syncthreads();
  int cur = 0;
  for (int k0 = 0; k0 < K; k0 += BK) {
    if (k0 + BK < K) STAGE(cur ^ 1, k0 + BK);
    #pragma unroll
    for (int kk = 0; kk < 2; ++kk) {
      short8 af[MR], bfr[NR];
      #pragma unroll
      for (int m = 0; m < MR; ++m) {
        const int row = wm * WM + m * 16 + l15;
        af[m] = *(const short8*)(&lA[cur][row * BK + ((((kk << 2) + g) ^ (row & 7)) << 3)]);
      }
      #pragma unroll
      for (int n = 0; n < NR; ++n) {
        const int row = wn * WN + n * 16 + l15;
        bfr[n] = *(const short8*)(&lB[cur][row * BK + ((((kk << 2) + g) ^ (row & 7)) << 3)]);
      }
      #pragma unroll
      for (int m = 0; m < MR; ++m)
        #pragma unroll
        for (int n = 0; n < NR; ++n)
          acc[m][n] = __builtin_amdgcn_mfma_f32_16x16x32_bf16(af[m], bfr[n], acc[m][n], 0, 0, 0);
    }
    __syncthreads();
    cur ^= 1;
  }
#undef STAGE

  const float* bp = bias ? (bias + off3(obias, z)) : nullptr;
  if constexpr (QKV) {
    #pragma unroll
    for (int m = 0; m < MR; ++m) {
      const long long row0 = bm + wm * WM + m * 16 + g * 4;
      const int b = (int)(row0 >> 10), tt = (int)(row0 & 1023);
      #pragma unroll
      for (int n = 0; n < NR; ++n) {
        const int col = (int)(bn + wn * WN + n * 16 + l15);
        const float bv = bp[col];
        const int sec = col >> 9, d = col & 511;
        u16 vb[4];
        #pragma unroll
        for (int r = 0; r < 4; ++r) vb[r] = f2b(acc[m][n][r] + bv);
        if (sec == 0) {
          #pragma unroll
          for (int r = 0; r < 4; ++r)
            ((u16*)Cv)[(row0 + r) * 512 + d] = vb[r];
        } else {
          u16* dst = (sec == 1 ? kTo : vTo);
          ushort4 p4; p4.x = vb[0]; p4.y = vb[1]; p4.z = vb[2]; p4.w = vb[3];
          *(ushort4*)(dst + (size_t)(b * 8 + (d >> 6)) * 65536 + (size_t)(d & 63) * 1024 + tt) = p4;
        }
      }
    }
  } else {
    #pragma unroll
    for (int m = 0; m < MR; ++m) {
      const long long row0 = bm + wm * WM + m * 16 + g * 4;
      #pragma unroll
      for (int n = 0; n < NR; ++n) {
        const long long col = bn + wn * WN + n * 16 + l15;
        const float bv = bp ? bp[col] : 0.0f;
        #pragma unroll
        for (int r = 0; r < 4; ++r) {
          float v = acc[m][n][r] * alpha + bv;
          if (ACT == 1) v = fmaxf(v, 0.0f);
          const long long idx = cb + (row0 + r) * (long long)ldc + col;
          if constexpr (C_BF16) ((u16*)Cv)[idx] = f2b(v);
          else                  ((float*)Cv)[idx] = v;
        }
      }
    }
  }
}

// ---------- sum 4 split-K partials -> bf16 ----------
__global__ __launch_bounds__(256) void mt_combine_kernel(
    const float* __restrict__ part, u16* __restrict__ out)
{
  const int i = blockIdx.x * 256 + threadIdx.x;
  const float s = part[i] + part[i + 524288] + part[i + 2 * 524288] + part[i + 3 * 524288];
  out[i] = f2b(s);
}

// ---------- fused attention tail (v4: 32x32 MFMA, 32t/wave, dbuf 32-s chunks) ----------
// block (tb, sp, z): 128 t (4 waves x 32), s in [sp*512, +512), 16 chunks of 32 s.
// rec: P^T[s][t] = mfma32(wd_frag, lat_frag); pe = exp(sigmoid(.+bd));
// PV A-frag rebuilt in-register (cvt_pk + 1 shfl_xor/word-pair); o += P@v.
__global__ __launch_bounds__(256, 2) void attn_tail_kernel(
    const u16* __restrict__ lat, const u16* __restrict__ wdT,
    const float* __restrict__ bd, const u16* __restrict__ vT,
    float* __restrict__ o_part, float* __restrict__ rs_part)
{
  __shared__ alignas(16) u16 wdL[2][32 * 256];   // 2 x 16 KB: [s:32][u:256]
  __shared__ alignas(16) u16 vL[2][64 * 32];     // 2 x 4 KB : [d:64][s:32]
  const int z = blockIdx.z, sp = blockIdx.y, tb = blockIdx.x, h8 = z & 7;
  const int lane = threadIdx.x & 63, wave = threadIdx.x >> 6;
  const int l31 = lane & 31, h = lane >> 5;
  const int s0 = sp * 512;
  const u16* latz = lat + (size_t)z * 262144 + (size_t)tb * 128 * 256;
  const u16* wdh  = wdT + (size_t)h8 * 262144;
  const float* bdh = bd + (size_t)h8 * 1024 + s0;
  const u16* vz = vT + (size_t)z * 65536 + s0;

  // lat fragments: B-op for 32x32x16: col t = wave*32+l31, k = h*8+j; 16 kg of 16 u
  short8 latf[16];
  {
    const u16* lp = latz + (size_t)(wave * 32 + l31) * 256 + h * 8;
    #pragma unroll
    for (int kg = 0; kg < 16; ++kg) latf[kg] = *(const short8*)(lp + kg * 16);
  }

  f32x16 oacc[2] = {};
  float rsum = 0.f;

#define ASTAGE(buf, sc)                                                          \
  {                                                                              \
    const int sb_ = (sc) * 32;                                                   \
    _Pragma("unroll")                                                            \
    for (int j = 0; j < 4; ++j) {                                                \
      const int c = j * 256 + threadIdx.x;                                       \
      const int row = c >> 5, slot = c & 31;                                     \
      __builtin_amdgcn_global_load_lds(                                          \
          (gas_p)(wdh + (size_t)(s0 + sb_ + row) * 256 + ((slot ^ (row & 7)) << 3)), \
          (las_p)(&wdL[buf][c * 8]), 16, 0, 0);                                  \
    }                                                                            \
    {                                                                            \
      const int c = threadIdx.x;                                                 \
      const int row = c >> 2, slot = c & 3;                                      \
      __builtin_amdgcn_global_load_lds(                                          \
          (gas_p)(vz + (size_t)row * 1024 + sb_ + ((slot ^ (row & 3)) << 3)),    \
          (las_p)(&vL[buf][c * 8]), 16, 0, 0);                                   \
    }                                                                            \
  }

  ASTAGE(0, 0);
  __syncthreads();
  int cur = 0;
  for (int sc = 0; sc < 16; ++sc) {
    if (sc < 15) ASTAGE(cur ^ 1, sc + 1);

    // rec: pacc = P^T frag (s' = (r&3)+8(r>>2)+4h, t = l31)
    f32x16 pacc = {};
    #pragma unroll
    for (int kg = 0; kg < 16; ++kg) {
      const short8 a = *(const short8*)(&wdL[cur][l31 * 256 + (((kg * 2 + h) ^ (l31 & 7)) << 3)]);
      pacc = __builtin_amdgcn_mfma_f32_32x32x16_bf16(a, latf[kg], pacc, 0, 0, 0);
    }

    // epilogue: pe = exp(sigmoid(pacc + bd))
    const int sb = sc * 32;
    float pe[16];
    #pragma unroll
    for (int p4 = 0; p4 < 4; ++p4) {
      const float4 b4 = *(const float4*)(bdh + sb + p4 * 8 + 4 * h);
      #pragma unroll
      for (int q = 0; q < 4; ++q) {
        const int r = p4 * 4 + q;
        const float val = pacc[r] + ((const float*)&b4)[q];
        const float sig = 1.0f / (1.0f + __expf(-val));
        pe[r] = __expf(sig);
        rsum += pe[r];
      }
    }

    // PV: per k2 (16 s), rebuild A-frag, 2 mfma over d
    #pragma unroll
    for (int k2 = 0; k2 < 2; ++k2) {
      const int rb = 8 * k2;
      unsigned wloA, wloB, whiA, whiB;
      asm("v_cvt_pk_bf16_f32 %0, %1, %2" : "=v"(wloA) : "v"(pe[rb]),     "v"(pe[rb + 1]));
      asm("v_cvt_pk_bf16_f32 %0, %1, %2" : "=v"(wloB) : "v"(pe[rb + 2]), "v"(pe[rb + 3]));
      asm("v_cvt_pk_bf16_f32 %0, %1, %2" : "=v"(whiA) : "v"(pe[rb + 4]), "v"(pe[rb + 5]));
      asm("v_cvt_pk_bf16_f32 %0, %1, %2" : "=v"(whiB) : "v"(pe[rb + 6]), "v"(pe[rb + 7]));
      const unsigned xA = h ? wloA : whiA;
      const unsigned rA = (unsigned)__shfl_xor((int)xA, 32);
      const unsigned xB = h ? wloB : whiB;
      const unsigned rB = (unsigned)__shfl_xor((int)xB, 32);
      short8 pa;
      ((unsigned*)&pa)[0] = h ? rA : wloA;
      ((unsigned*)&pa)[1] = h ? rB : wloB;
      ((unsigned*)&pa)[2] = h ? whiA : rA;
      ((unsigned*)&pa)[3] = h ? whiB : rB;
      #pragma unroll
      for (int nd = 0; nd < 2; ++nd) {
        const int d = nd * 32 + l31;
        const short8 vb = *(const short8*)(&vL[cur][d * 32 + (((k2 * 2 + h) ^ (d & 3)) << 3)]);
        oacc[nd] = __builtin_amdgcn_mfma_f32_32x32x16_bf16(pa, vb, oacc[nd], 0, 0, 0);
      }
    }
    __syncthreads();
    cur ^= 1;
  }
#undef ASTAGE

  rsum += __shfl_xor(rsum, 32);
  const long long orow0 = (long long)(z >> 3) * 1024 + tb * 128 + wave * 32;
  float* op = o_part + (size_t)sp * ((size_t)BT * EE);
  #pragma unroll
  for (int nd = 0; nd < 2; ++nd)
    #pragma unroll
    for (int r = 0; r < 16; ++r) {
      const int trow = (r & 3) + 8 * (r >> 2) + 4 * h;
      op[(orow0 + trow) * 512 + h8 * 64 + nd * 32 + l31] = oacc[nd][r];
    }
  if (h == 0)
    rs_part[(size_t)sp * 32768 + (size_t)z * 1024 + tb * 128 + wave * 32 + l31] = rsum;
}

// ---------- combine partials: o = (o0+o1) / (rs0+rs1), bf16 ----------
__global__ __launch_bounds__(256) void attn_combine_kernel(
    const float* __restrict__ o_part, const float* __restrict__ rs_part,
    u16* __restrict__ o)
{
  const int row = blockIdx.x;
  const int b = row >> 10, t = row & 1023;
  #pragma unroll
  for (int j = 0; j < 2; ++j) {
    const int c = j * 256 + threadIdx.x;
    const int bh = b * 8 + (c >> 6);
    const float rs = rs_part[(size_t)bh * 1024 + t] + rs_part[32768 + (size_t)bh * 1024 + t];
    const float v = (o_part[(size_t)row * 512 + c] +
                     o_part[(size_t)BT * EE + (size_t)row * 512 + c]) / rs;
    o[(size_t)row * 512 + c] = f2b(v);
  }
}

// ---------- embedding ----------
__global__ __launch_bounds__(256) void embed_kernel(
    const float* __restrict__ tok, const float* __restrict__ pos,
    const int* __restrict__ x, float* __restrict__ h, u16* __restrict__ hb)
{
  const long long row = blockIdx.x;
  const int t = (int)(row & (TT - 1));
  const long long tokid = x[row];
  const float* te = tok + tokid * EE;
  const float* pe = pos + (long long)t * EE;
  const long long base = row * EE;
  for (int e = threadIdx.x; e < EE; e += 256) {
    float v = te[e] + pe[e];
    h[base + e] = v;
    hb[base + e] = f2b(v);
  }
}

// ---------- residual + layernorm (bf16 delta) ----------
__global__ __launch_bounds__(256) void addnorm_kernel(
    const float* __restrict__ hin, const u16* __restrict__ delta,
    const float* __restrict__ g, const float* __restrict__ bta,
    float* __restrict__ hout, u16* __restrict__ hbout)
{
  __shared__ float sm[8];
  const long long base = (long long)blockIdx.x * EE;
  const int tid = threadIdx.x;
  float x0 = hin[base + tid] + b2f(delta[base + tid]);
  float x1 = hin[base + tid + 256] + b2f(delta[base + tid + 256]);
  float s = x0 + x1, ss = x0 * x0 + x1 * x1;
  #pragma unroll
  for (int o = 32; o; o >>= 1) { s += __shfl_down(s, o); ss += __shfl_down(ss, o); }
  if ((tid & 63) == 0) { sm[tid >> 6] = s; sm[4 + (tid >> 6)] = ss; }
  __syncthreads();
  const float S = sm[0] + sm[1] + sm[2] + sm[3];
  const float SS = sm[4] + sm[5] + sm[6] + sm[7];
  const float mu = S * (1.0f / EE);
  const float var = SS * (1.0f / EE) - mu * mu;
  const float inv = rsqrtf(var + 1e-5f);
  const float y0 = (x0 - mu) * inv * g[tid] + bta[tid];
  const float y1 = (x1 - mu) * inv * g[tid + 256] + bta[tid + 256];
  hout[base + tid] = y0;       hout[base + tid + 256] = y1;
  hbout[base + tid] = f2b(y0); hbout[base + tid + 256] = f2b(y1);
}

// ---------- LDS-tiled transpose-convert ----------
template<typename ST>
__global__ __launch_bounds__(256) void transposeT_kernel(
    u16* __restrict__ dst, const ST* __restrict__ src,
    int ldsrc, int lddst, Off3 dstz, Off3 srcz)
{
  __shared__ float t[32][33];
  const int z = blockIdx.z;
  const ST* s = src + off3(srcz, z);
  u16* d = dst + off3(dstz, z);
  const int r0 = blockIdx.x * 32, c0 = blockIdx.y * 32;
  const int tx = threadIdx.x & 31, ty = threadIdx.x >> 5;
  #pragma unroll
  for (int j = 0; j < 4; ++j) {
    const int r = ty + j * 8;
    t[r][tx] = tof(s[(long long)(r0 + r) * ldsrc + c0 + tx]);
  }
  __syncthreads();
  #pragma unroll
  for (int j = 0; j < 4; ++j) {
    const int c = ty + j * 8;
    d[(long long)(c0 + c) * lddst + r0 + tx] = f2b(t[tx][c]);
  }
}

// ---------- stack bq|bk|bv per layer ----------
__global__ __launch_bounds__(256) void biaspack_kernel(
    float* __restrict__ dst, const float* __restrict__ bq,
    const float* __restrict__ bk, const float* __restrict__ bv)
{
  const int i = blockIdx.x * 256 + threadIdx.x;
  if (i >= LL * 1536) return;
  const int l = i / 1536, j = i % 1536;
  dst[i] = (j < 512) ? bq[l * 512 + j]
         : (j < 1024) ? bk[l * 512 + j - 512]
                      : bv[l * 512 + j - 1024];
}

__global__ void finalize_loss(float* out) { out[0] = LAMBDA * (float)(LL * 32 * 1024); }

// ---------- host ----------
extern "C" void kernel_launch(void* const* d_in, const int* in_sizes, int n_in,
                              void* d_out, int out_size, void* d_ws, size_t ws_size,
                              hipStream_t stream)
{
  (void)in_sizes; (void)n_in; (void)out_size; (void)ws_size;
  const float* tok = (const float*)d_in[0];
  const float* pos = (const float*)d_in[1];
  const float* wq  = (const float*)d_in[2];
  const float* bq  = (const float*)d_in[3];
  const float* wk  = (const float*)d_in[4];
  const float* bk  = (const float*)d_in[5];
  const float* wv  = (const float*)d_in[6];
  const float* bv  = (const float*)d_in[7];
  const float* we  = (const float*)d_in[8];
  const float* be  = (const float*)d_in[9];
  const float* wd  = (const float*)d_in[10];
  const float* bd  = (const float*)d_in[11];
  const float* wo  = (const float*)d_in[12];
  const float* bo  = (const float*)d_in[13];
  const float* ln1g = (const float*)d_in[14];
  const float* ln1b = (const float*)d_in[15];
  const float* w1  = (const float*)d_in[16];
  const float* b1  = (const float*)d_in[17];
  const float* w2  = (const float*)d_in[18];
  const float* b2  = (const float*)d_in[19];
  const float* ln2g = (const float*)d_in[20];
  const float* ln2b = (const float*)d_in[21];
  const int*   x   = (const int*)d_in[22];

  char* ws = (char*)d_ws;
  size_t off = 0;
  auto alloc = [&](size_t bytes) { void* p = ws + off; off = (off + bytes + 255) & ~255ULL; return p; };

  u16*  wqkvT = (u16*)alloc((size_t)LL * 3 * 512 * 512 * 2);
  u16*  weT   = (u16*)alloc((size_t)LL * HH * T4 * TT * 2);
  u16*  wdT   = (u16*)alloc((size_t)LL * HH * TT * T4 * 2);
  u16*  woT   = (u16*)alloc((size_t)LL * EE * EE * 2);
  u16*  w1T   = (u16*)alloc((size_t)LL * FF * EE * 2);
  u16*  w2T   = (u16*)alloc((size_t)LL * EE * FF * 2);
  float* bqkv = (float*)alloc((size_t)LL * 1536 * 4);
  float* h_f  = (float*)alloc((size_t)BT * EE * 4);
  u16*  h_b   = (u16*)alloc((size_t)BT * EE * 2);
  u16*  q_b   = (u16*)alloc((size_t)BT * EE * 2);
  u16*  kT_b  = (u16*)alloc((size_t)32 * HD * TT * 2);
  u16*  vT_b  = (u16*)alloc((size_t)32 * HD * TT * 2);
  u16*  MT_b  = (u16*)alloc((size_t)32 * T4 * HD * 2);
  float* MT_part = (float*)alloc((size_t)4 * 32 * T4 * HD * 4);
  u16*  lat_b = (u16*)alloc((size_t)32 * TT * T4 * 2);
  u16*  o_b   = (u16*)alloc((size_t)BT * EE * 2);
  u16*  attn_d = (u16*)alloc((size_t)BT * EE * 2);
  u16*  ff2_d  = (u16*)alloc((size_t)BT * EE * 2);
  u16*  ff1_b = (u16*)alloc((size_t)BT * FF * 2);
  float* o_part = (float*)alloc((size_t)2 * BT * EE * 4);
  float* rs_part = (float*)alloc((size_t)2 * 32 * 1024 * 4);

  const Off3 Z1 = {0, 0, 1};

  embed_kernel<<<dim3(BT), 256, 0, stream>>>(tok, pos, x, h_f, h_b);
  biaspack_kernel<<<dim3((LL * 1536 + 255) / 256), 256, 0, stream>>>(bqkv, bq, bk, bv);

  transposeT_kernel<float><<<dim3(16, 2, 48), 256, 0, stream>>>(
      wqkvT,          wq, 64, 512, Off3{786432, 32768, 8}, Off3{32768, 0, 1});
  transposeT_kernel<float><<<dim3(16, 2, 48), 256, 0, stream>>>(
      wqkvT + 262144, wk, 64, 512, Off3{786432, 32768, 8}, Off3{32768, 0, 1});
  transposeT_kernel<float><<<dim3(16, 2, 48), 256, 0, stream>>>(
      wqkvT + 524288, wv, 64, 512, Off3{786432, 32768, 8}, Off3{32768, 0, 1});
  transposeT_kernel<float><<<dim3(32, 8, 48), 256, 0, stream>>>(
      weT, we, 256, 1024, Off3{262144, 0, 1}, Off3{262144, 0, 1});
  transposeT_kernel<float><<<dim3(8, 32, 48), 256, 0, stream>>>(
      wdT, wd, 1024, 256, Off3{262144, 0, 1}, Off3{262144, 0, 1});
  transposeT_kernel<float><<<dim3(16, 16, 6), 256, 0, stream>>>(
      woT, wo, 512, 512, Off3{262144, 0, 1}, Off3{262144, 0, 1});
  transposeT_kernel<float><<<dim3(16, 64, 6), 256, 0, stream>>>(
      w1T, w1, 2048, 512, Off3{1048576, 0, 1}, Off3{1048576, 0, 1});
  transposeT_kernel<float><<<dim3(64, 16, 6), 256, 0, stream>>>(
      w2T, w2, 512, 2048, Off3{1048576, 0, 1}, Off3{1048576, 0, 1});

  for (int l = 0; l < LL; ++l) {
    // --- fused q|k|v projection; q row-major, k/v transposed per head ---
    gemm_p<64, 128, true, 0, false, true><<<dim3(64, 12, 1), 256, 0, stream>>>(
        h_b, wqkvT + (size_t)l * 786432, q_b, bqkv + l * 1536, 1.0f,
        512, 512, 512, 512, Z1, Z1, Z1, Z1, 0, kT_b, vT_b);

    // --- MT[u][d] = sum_s we[s][u] k[s][d] : split-K x4 ---
    gemm_p<64, 64, false, 0, true, false><<<dim3(4, 4, 32), 256, 0, stream>>>(
        weT + (size_t)l * 2097152, kT_b, MT_part, nullptr, 1.0f,
        256, 1024, 1024, 64,
        Off3{0, 262144, 8}, Off3{65536, 0, 1}, Off3{16384, 0, 1}, Z1, 524288,
        nullptr, nullptr);
    mt_combine_kernel<<<dim3(2048), 256, 0, stream>>>(MT_part, MT_b);

    // --- lat = relu(0.125 * q @ MT^T + be) ---
    gemm_p<64, 128, true, 1, false, false><<<dim3(16, 2, 32), 256, 0, stream>>>(
        q_b, MT_b, lat_b, be + l * 2048, 0.125f,
        64, 512, 64, 256,
        Off3{524288, 64, 8}, Off3{16384, 0, 1}, Off3{262144, 0, 1}, Off3{0, 256, 8}, 0,
        nullptr, nullptr);

    // --- fused: P = exp(sigmoid(lat@wd+bd)); partial O and rowsum per s-half ---
    attn_tail_kernel<<<dim3(8, 2, 32), 256, 0, stream>>>(
        lat_b, wdT + (size_t)l * 2097152, bd + (size_t)l * 8192, vT_b, o_part, rs_part);
    attn_combine_kernel<<<dim3(BT), 256, 0, stream>>>(o_part, rs_part, o_b);

    // --- attn out projection ---
    gemm_p<64, 64, true, 0, false, false><<<dim3(64, 8, 1), 256, 0, stream>>>(
        o_b, woT + (size_t)l * 262144, attn_d, bo + l * 512, 1.0f,
        512, 512, 512, 512, Z1, Z1, Z1, Z1, 0, nullptr, nullptr);

    addnorm_kernel<<<dim3(BT), 256, 0, stream>>>(h_f, attn_d, ln1g + l * 512, ln1b + l * 512, h_f, h_b);

    // --- FFN ---
    gemm_p<64, 128, true, 1, false, false><<<dim3(64, 16, 1), 256, 0, stream>>>(
        h_b, w1T + (size_t)l * 1048576, ff1_b, b1 + l * 2048, 1.0f,
        512, 512, 512, 2048, Z1, Z1, Z1, Z1, 0, nullptr, nullptr);
    gemm_p<64, 64, true, 1, false, false><<<dim3(64, 8, 1), 256, 0, stream>>>(
        ff1_b, w2T + (size_t)l * 1048576, ff2_d, b2 + l * 512, 1.0f,
        2048, 2048, 2048, 512, Z1, Z1, Z1, Z1, 0, nullptr, nullptr);

    float* hout = (l == LL - 1) ? (float*)d_out : h_f;
    addnorm_kernel<<<dim3(BT), 256, 0, stream>>>(h_f, ff2_d, ln2g + l * 512, ln2b + l * 512, hout, h_b);
  }

  finalize_loss<<<1, 1, 0, stream>>>((float*)d_out + (size_t)BT * EE);
}